// Round 5
// baseline (405.286 us; speedup 1.0000x reference)
//
#include <hip/hip_runtime.h>

typedef __attribute__((ext_vector_type(4))) float f32x4;
typedef __attribute__((ext_vector_type(8))) __bf16 bf16x8;
typedef __attribute__((ext_vector_type(4))) unsigned short u16x4;

#define DEVI static __device__ __forceinline__
#define AS1 __attribute__((address_space(1)))
#define AS3 __attribute__((address_space(3)))

static constexpr int S_LEN = 2048;
static constexpr int HID   = 4096;
static constexpr int NH    = 32;
static constexpr int NKV   = 8;
static constexpr int HD    = 128;
static constexpr int NQKV  = HID + 2 * NKV * HD;   // 6144

DEVI unsigned short f2bf(float f) {
  unsigned int u = __float_as_uint(f);
  u += 0x7FFFu + ((u >> 16) & 1u);
  return (unsigned short)(u >> 16);
}
DEVI float bf2f(unsigned short h) {
  return __uint_as_float(((unsigned int)h) << 16);
}

// ---------------- fp32 -> bf16 cast (float4 vectorized) ----------------
__global__ void cast_f32_bf16(const float* __restrict__ in,
                              unsigned short* __restrict__ out, int n4) {
  int i = blockIdx.x * 256 + threadIdx.x;
  if (i >= n4) return;
  float4 v = reinterpret_cast<const float4*>(in)[i];
  u16x4 o;
  o[0] = f2bf(v.x); o[1] = f2bf(v.y); o[2] = f2bf(v.z); o[3] = f2bf(v.w);
  reinterpret_cast<u16x4*>(out)[i] = o;
}

// ---------------- RoPE cos/sin table [S][64] float2 ----------------
__global__ void rope_table(float2* __restrict__ tab) {
  int i = blockIdx.x * 256 + threadIdx.x;
  if (i >= S_LEN * 64) return;
  int j = i & 63, s = i >> 6;
  float inv = powf(10000.0f, -(float)j / 64.0f);
  float ang = (float)s * inv;
  tab[i] = make_float2(cosf(ang), sinf(ang));
}

// ---------------- RoPE in place on bf16 [S][Hn*128] ----------------
__global__ void rope_kernel(unsigned short* __restrict__ X,
                            const float2* __restrict__ tab, int Hn, int total) {
  int i = blockIdx.x * 256 + threadIdx.x;
  if (i >= total) return;
  int j = i & 63;              // freq index 0..63
  int h = (i >> 6) % Hn;
  int s = i / (64 * Hn);
  float2 cs = tab[s * 64 + j];
  unsigned short* p = X + (size_t)s * Hn * HD + h * HD;
  float x1 = bf2f(p[j]);
  float x2 = bf2f(p[j + 64]);
  p[j]      = f2bf(x1 * cs.x - x2 * cs.y);
  p[j + 64] = f2bf(x2 * cs.x + x1 * cs.y);
}

// ============ fused QKV GEMM, 256x256 tile, BK=64, 8-wave, 8-phase ============
// C[2048 x 6144] = H @ Wcat^T. Epilogue routes by block col: Q / K / V^T.
// Grid is FLAT 192 blocks; by = bid&7 so each XCD (bid%8) owns one A-panel row
// (2 MB, L2-resident); bx = bid>>3.
//
// vmcnt discipline (T4): per-phase vmcnt(6) = 3 half-tiles in flight; the
// drain targets the stage issued 4 phases back (~600 cy, lands free).
// Queue trace (steady state, 2 loads/phase): at P_k entry outstanding = 8,
// drain 2 oldest = the stage first-read THIS phase. Last iteration peeled:
// P4-P8 stop issuing, queues shrink below 6, so P5 takes vmcnt(0) (covers
// P1-P3's stages read at P5-P8).  Stage placement unchanged from r4
// (stage->first-read distance 4-5 phases; write-after-read per-phase safe).
__global__ __launch_bounds__(512, 2) void gemm_qkv256(
    const unsigned short* __restrict__ A,   // [2048][4096]
    const unsigned short* __restrict__ B,   // [6144][4096]
    unsigned short* __restrict__ Qb,
    unsigned short* __restrict__ Kb,
    unsigned short* __restrict__ Vt) {
  __shared__ __align__(16) unsigned short lds[2][32768];
  const int tid = threadIdx.x;
  const int lane = tid & 63, w = tid >> 6;
  const int wm = w >> 2, wn = w & 3;
  const int lr = lane & 15, lg = lane >> 4;
  const int by = blockIdx.x & 7, bx = blockIdx.x >> 3;  // XCD-chunked mapping
  const int m0 = by * 256, n0 = bx * 256;
  const int Kd = HID;

  const int sAr = tid >> 3, sAp = tid & 7;   // A stage: row-in-band, phys chunk
  const int sBn = tid >> 2, sBp = tid & 3;   // B stage: row-in-half, phys chunk
  auto stageA = [&](int buf, int t, int band) {
    int row = band * 64 + sAr;
    __builtin_amdgcn_global_load_lds(
        (const AS1 void*)(A + (size_t)(m0 + row) * Kd + t * 64 + ((sAp ^ (row & 7)) * 8)),
        (AS3 void*)(&lds[buf][row * 64 + sAp * 8]), 16, 0, 0);
  };
  auto stageB = [&](int buf, int t, int kh, int hb) {
    int n = hb * 128 + sBn;
    __builtin_amdgcn_global_load_lds(
        (const AS1 void*)(B + (size_t)(n0 + n) * Kd + t * 64 + kh * 32 + ((sBp ^ ((n >> 1) & 3)) * 8)),
        (AS3 void*)(&lds[buf][16384 + kh * 8192 + n * 32 + sBp * 8]), 16, 0, 0);
  };

  // ds_read element offsets (row&7 == lr&7, (n>>1)&3 == (lr>>1)&3)
  const int aoff0 = (wm * 128 + lr) * 64 + ((lg ^ (lr & 7)) * 8);        // kh=0
  const int aoff1 = (wm * 128 + lr) * 64 + (((4 + lg) ^ (lr & 7)) * 8);  // kh=1
  const int boff  = 16384 + (wn * 64 + lr) * 32 + ((lg ^ ((lr >> 1) & 3)) * 8);

  f32x4 acc[8][4] = {};

  // prologue: fully stage tiles 0 (buf0) and 1 (buf1)
#pragma unroll
  for (int b = 0; b < 4; ++b) { stageA(0, 0, b); stageA(1, 1, b); }
#pragma unroll
  for (int kh = 0; kh < 2; ++kh)
#pragma unroll
    for (int hb = 0; hb < 2; ++hb) { stageB(0, 0, kh, hb); stageB(1, 1, kh, hb); }
  asm volatile("s_waitcnt vmcnt(0)" ::: "memory");
  __builtin_amdgcn_s_barrier();

#define PHASE(BUF, MH, KH, WAIT, ...)                                          \
  do {                                                                         \
    asm volatile("s_waitcnt vmcnt(" WAIT ")" ::: "memory");                    \
    const unsigned short* ab = &lds[BUF][((KH) ? aoff1 : aoff0) + (MH) * 4096];\
    bf16x8 af0 = *reinterpret_cast<const bf16x8*>(ab);                         \
    bf16x8 af1 = *reinterpret_cast<const bf16x8*>(ab + 1024);                  \
    bf16x8 af2 = *reinterpret_cast<const bf16x8*>(ab + 2048);                  \
    bf16x8 af3 = *reinterpret_cast<const bf16x8*>(ab + 3072);                  \
    const unsigned short* bb = &lds[BUF][boff + (KH) * 8192];                  \
    bf16x8 bg0 = *reinterpret_cast<const bf16x8*>(bb);                         \
    bf16x8 bg1 = *reinterpret_cast<const bf16x8*>(bb + 512);                   \
    bf16x8 bg2 = *reinterpret_cast<const bf16x8*>(bb + 1024);                  \
    bf16x8 bg3 = *reinterpret_cast<const bf16x8*>(bb + 1536);                  \
    __VA_ARGS__                                                                \
    __builtin_amdgcn_s_barrier();                                              \
    asm volatile("s_waitcnt lgkmcnt(0)" ::: "memory");                         \
    __builtin_amdgcn_sched_barrier(0);                                         \
    __builtin_amdgcn_s_setprio(1);                                             \
    acc[(MH)*4+0][0] = __builtin_amdgcn_mfma_f32_16x16x32_bf16(af0, bg0, acc[(MH)*4+0][0],0,0,0); \
    acc[(MH)*4+0][1] = __builtin_amdgcn_mfma_f32_16x16x32_bf16(af0, bg1, acc[(MH)*4+0][1],0,0,0); \
    acc[(MH)*4+0][2] = __builtin_amdgcn_mfma_f32_16x16x32_bf16(af0, bg2, acc[(MH)*4+0][2],0,0,0); \
    acc[(MH)*4+0][3] = __builtin_amdgcn_mfma_f32_16x16x32_bf16(af0, bg3, acc[(MH)*4+0][3],0,0,0); \
    acc[(MH)*4+1][0] = __builtin_amdgcn_mfma_f32_16x16x32_bf16(af1, bg0, acc[(MH)*4+1][0],0,0,0); \
    acc[(MH)*4+1][1] = __builtin_amdgcn_mfma_f32_16x16x32_bf16(af1, bg1, acc[(MH)*4+1][1],0,0,0); \
    acc[(MH)*4+1][2] = __builtin_amdgcn_mfma_f32_16x16x32_bf16(af1, bg2, acc[(MH)*4+1][2],0,0,0); \
    acc[(MH)*4+1][3] = __builtin_amdgcn_mfma_f32_16x16x32_bf16(af1, bg3, acc[(MH)*4+1][3],0,0,0); \
    acc[(MH)*4+2][0] = __builtin_amdgcn_mfma_f32_16x16x32_bf16(af2, bg0, acc[(MH)*4+2][0],0,0,0); \
    acc[(MH)*4+2][1] = __builtin_amdgcn_mfma_f32_16x16x32_bf16(af2, bg1, acc[(MH)*4+2][1],0,0,0); \
    acc[(MH)*4+2][2] = __builtin_amdgcn_mfma_f32_16x16x32_bf16(af2, bg2, acc[(MH)*4+2][2],0,0,0); \
    acc[(MH)*4+2][3] = __builtin_amdgcn_mfma_f32_16x16x32_bf16(af2, bg3, acc[(MH)*4+2][3],0,0,0); \
    acc[(MH)*4+3][0] = __builtin_amdgcn_mfma_f32_16x16x32_bf16(af3, bg0, acc[(MH)*4+3][0],0,0,0); \
    acc[(MH)*4+3][1] = __builtin_amdgcn_mfma_f32_16x16x32_bf16(af3, bg1, acc[(MH)*4+3][1],0,0,0); \
    acc[(MH)*4+3][2] = __builtin_amdgcn_mfma_f32_16x16x32_bf16(af3, bg2, acc[(MH)*4+3][2],0,0,0); \
    acc[(MH)*4+3][3] = __builtin_amdgcn_mfma_f32_16x16x32_bf16(af3, bg3, acc[(MH)*4+3][3],0,0,0); \
    __builtin_amdgcn_s_setprio(0);                                             \
    __builtin_amdgcn_s_barrier();                                              \
  } while (0)

  for (int i = 0; i < 31; ++i) {
    const int t = 2 * i;
    const bool nf = (i != 0);
    PHASE(0, 0, 0, "6", if (nf) { stageB(1, t + 1, 0, 0); stageB(1, t + 1, 0, 1); });
    PHASE(0, 0, 1, "6", if (nf) { stageB(1, t + 1, 1, 0); stageB(1, t + 1, 1, 1); });
    PHASE(0, 1, 0, "6", if (nf) { stageA(1, t + 1, 1); stageA(1, t + 1, 3); });
    PHASE(0, 1, 1, "6", { stageB(0, t + 2, 0, 0); stageB(0, t + 2, 0, 1); });
    PHASE(1, 0, 0, "6", { stageA(0, t + 2, 0); stageA(0, t + 2, 2); });
    PHASE(1, 0, 1, "6", { stageB(0, t + 2, 1, 0); stageB(0, t + 2, 1, 1); });
    PHASE(1, 1, 0, "6", { stageA(0, t + 2, 1); stageA(0, t + 2, 3); });
    PHASE(1, 1, 1, "6", { stageA(1, t + 3, 0); stageA(1, t + 3, 2); });
  }
  {  // peeled last iteration (t=62): no new stages after P3; P5 drains all
    const int t = 62;
    PHASE(0, 0, 0, "6", { stageB(1, t + 1, 0, 0); stageB(1, t + 1, 0, 1); });
    PHASE(0, 0, 1, "6", { stageB(1, t + 1, 1, 0); stageB(1, t + 1, 1, 1); });
    PHASE(0, 1, 0, "6", { stageA(1, t + 1, 1); stageA(1, t + 1, 3); });
    PHASE(0, 1, 1, "6", ;);
    PHASE(1, 0, 0, "0", ;);
    PHASE(1, 0, 1, "6", ;);
    PHASE(1, 1, 0, "6", ;);
    PHASE(1, 1, 1, "6", ;);
  }
#undef PHASE

  // epilogue: route by block col region (bx<16: Q, <20: K, else V transposed)
#pragma unroll
  for (int ar = 0; ar < 8; ++ar) {
#pragma unroll
    for (int fc = 0; fc < 4; ++fc) {
      const int gcol = n0 + wn * 64 + fc * 16 + lr;
      const int growb = m0 + wm * 128 + (ar >> 2) * 64 + (ar & 3) * 16 + lg * 4;
      if (bx < 16) {
#pragma unroll
        for (int rr = 0; rr < 4; ++rr)
          Qb[(size_t)(growb + rr) * HID + gcol] = f2bf(acc[ar][fc][rr]);
      } else if (bx < 20) {
#pragma unroll
        for (int rr = 0; rr < 4; ++rr)
          Kb[(size_t)(growb + rr) * (NKV * HD) + (gcol - HID)] = f2bf(acc[ar][fc][rr]);
      } else {
        u16x4 o4;
#pragma unroll
        for (int rr = 0; rr < 4; ++rr) o4[rr] = f2bf(acc[ar][fc][rr]);
        *reinterpret_cast<u16x4*>(
            &Vt[(size_t)(gcol - HID - NKV * HD) * S_LEN + growb]) = o4;
      }
    }
  }
}

// ---------------- bf16 GEMM: C = A @ B^T (O-projection, fp32 out, m97) ----------------
__global__ __launch_bounds__(256) void gemm_bt(
    const unsigned short* __restrict__ A,
    const unsigned short* __restrict__ B,
    float* __restrict__ C, int M, int N, int Kd) {
  __shared__ __align__(16) unsigned short sA[128 * 32];
  __shared__ __align__(16) unsigned short sB[128 * 32];
  const int tid = threadIdx.x;
  const int lane = tid & 63, w = tid >> 6;
  const int wr = w >> 1, wc = w & 1;
  const int lr = lane & 15, lg = lane >> 4;
  const int m0 = blockIdx.y * 128, n0 = blockIdx.x * 128;

  f32x4 acc[4][4] = {};

  for (int k0 = 0; k0 < Kd; k0 += 32) {
#pragma unroll
    for (int r = 0; r < 2; ++r) {
      int e = (tid + r * 256) * 8;
      int row = e >> 5, col = e & 31;
      __builtin_amdgcn_global_load_lds(
          (const AS1 void*)(A + (size_t)(m0 + row) * Kd + k0 + col),
          (AS3 void*)(sA + e), 16, 0, 0);
      __builtin_amdgcn_global_load_lds(
          (const AS1 void*)(B + (size_t)(n0 + row) * Kd + k0 + col),
          (AS3 void*)(sB + e), 16, 0, 0);
    }
    __syncthreads();

    bf16x8 af[4], bfr[4];
#pragma unroll
    for (int m = 0; m < 4; ++m)
      af[m] = *reinterpret_cast<const bf16x8*>(&sA[(wr * 64 + m * 16 + lr) * 32 + lg * 8]);
#pragma unroll
    for (int n = 0; n < 4; ++n)
      bfr[n] = *reinterpret_cast<const bf16x8*>(&sB[(wc * 64 + n * 16 + lr) * 32 + lg * 8]);
#pragma unroll
    for (int m = 0; m < 4; ++m)
#pragma unroll
      for (int n = 0; n < 4; ++n)
        acc[m][n] = __builtin_amdgcn_mfma_f32_16x16x32_bf16(af[m], bfr[n], acc[m][n], 0, 0, 0);
    __syncthreads();
  }

#pragma unroll
  for (int m = 0; m < 4; ++m)
#pragma unroll
    for (int n = 0; n < 4; ++n) {
      int gcol = n0 + wc * 64 + n * 16 + lr;
#pragma unroll
      for (int r = 0; r < 4; ++r) {
        int grow = m0 + wr * 64 + m * 16 + lg * 4 + r;
        C[(size_t)grow * N + gcol] = acc[m][n][r];
      }
    }
}

// ---------------- causal GQA flash attention, swapped-QK^T, 8-wave ----------------
// K tile stride is 256 B -> bank16 = chunk only, so the swizzle must span all
// 16 chunks: c ^= (row&15) (r4's row&7 left a 4-way conflict, 6.5e6 counts).
// Softmax: log2-domain + T13 defer-max (skip rescale while tmax <= m+8).
__global__ __launch_bounds__(512, 4) void attn_kernel(
    const unsigned short* __restrict__ Q,   // [S][NH*HD]
    const unsigned short* __restrict__ Kb,  // [S][NKV*HD]
    const unsigned short* __restrict__ Vt,  // [NKV*HD][S]
    unsigned short* __restrict__ O) {       // [S][NH*HD]
  __shared__ __align__(16) unsigned short sK[2][64 * 128];
  __shared__ __align__(16) unsigned short sV[2][128 * 64];
  const int tid = threadIdx.x;
  const int lane = tid & 63, w = tid >> 6;
  const int lr = lane & 15, lg = lane >> 4;
  const int qt = (int)gridDim.x - 1 - (int)blockIdx.x;  // descending work order
  const int h = blockIdx.y, kvh = h >> 2;
  const int q0 = qt * 128, qw = q0 + w * 16;
  const int KVS = NKV * HD;

  bf16x8 qf[4];
#pragma unroll
  for (int ks = 0; ks < 4; ++ks)
    qf[ks] = *reinterpret_cast<const bf16x8*>(
        &Q[(size_t)(qw + lr) * HID + h * HD + ks * 32 + lg * 8]);

  f32x4 ao[8] = {};
  float mrun = -INFINITY, lrun = 0.f;   // mrun in log2 units
  const float S2 = 0.12751745f;         // (1/sqrt(128)) * log2(e)
  const int ntiles = 2 * qt + 2;

  auto stage = [&](int b, int kv0) {
#pragma unroll
    for (int i = 0; i < 2; ++i) {
      int off = (tid + i * 512) * 8;
      int r = off >> 7, c = (off >> 3) & 15;
      __builtin_amdgcn_global_load_lds(
          (const AS1 void*)(Kb + (size_t)(kv0 + r) * KVS + kvh * HD + ((c ^ (r & 15)) * 8)),
          (AS3 void*)(&sK[b][off]), 16, 0, 0);
    }
#pragma unroll
    for (int i = 0; i < 2; ++i) {
      int off = (tid + i * 512) * 8;
      int r = off >> 6, c = (off >> 3) & 7;
      __builtin_amdgcn_global_load_lds(
          (const AS1 void*)(Vt + (size_t)(kvh * HD + r) * S_LEN + kv0 + ((c ^ (r & 7)) * 8)),
          (AS3 void*)(&sV[b][off]), 16, 0, 0);
    }
  };

  stage(0, 0);
  __syncthreads();
  int cur = 0;

  for (int t = 0; t < ntiles; ++t) {
    const int kv0 = t * 64;
    if (t + 1 < ntiles) stage(cur ^ 1, kv0 + 64);

    if (kv0 <= qw + 15) {
      f32x4 sacc[4] = {};
      __builtin_amdgcn_s_setprio(1);
#pragma unroll
      for (int kt = 0; kt < 4; ++kt)
#pragma unroll
        for (int ks = 0; ks < 4; ++ks) {
          int elem = (kt * 16 + lr) * 128 + (((4 * ks + lg) ^ lr) * 8);
          bf16x8 kf = *reinterpret_cast<const bf16x8*>(&sK[cur][elem]);
          sacc[kt] = __builtin_amdgcn_mfma_f32_16x16x32_bf16(kf, qf[ks], sacc[kt], 0, 0, 0);
        }
      __builtin_amdgcn_s_setprio(0);

      const bool needMask = (kv0 + 63 > qw);
      const int qg = qw + lr;
      float p[16];
      float tmax = -INFINITY;
#pragma unroll
      for (int kt = 0; kt < 4; ++kt)
#pragma unroll
        for (int r = 0; r < 4; ++r) {
          float v = sacc[kt][r] * S2;
          if (needMask && (kv0 + kt * 16 + lg * 4 + r > qg)) v = -INFINITY;
          p[kt * 4 + r] = v;
          tmax = fmaxf(tmax, v);
        }
      tmax = fmaxf(tmax, __shfl_xor(tmax, 16));
      tmax = fmaxf(tmax, __shfl_xor(tmax, 32));
      // T13 defer-max: only rescale when max grew past threshold (log2 units)
      if (!__all(tmax <= mrun + 8.0f)) {
        float mnew = fmaxf(mrun, tmax);
        float corr = exp2f(mrun - mnew);
        lrun *= corr;
#pragma unroll
        for (int dt = 0; dt < 8; ++dt) ao[dt] *= corr;
        mrun = mnew;
      }
      float rs = 0.f;
#pragma unroll
      for (int i = 0; i < 16; ++i) { p[i] = exp2f(p[i] - mrun); rs += p[i]; }
      rs += __shfl_xor(rs, 16);
      rs += __shfl_xor(rs, 32);
      lrun += rs;

      unsigned int bfrag[2][4];
#pragma unroll
      for (int g = 0; g < 2; ++g) {
        unsigned int Au = (unsigned)f2bf(p[8 * g + 0]) | ((unsigned)f2bf(p[8 * g + 1]) << 16);
        unsigned int Bu = (unsigned)f2bf(p[8 * g + 2]) | ((unsigned)f2bf(p[8 * g + 3]) << 16);
        unsigned int Cu = (unsigned)f2bf(p[8 * g + 4]) | ((unsigned)f2bf(p[8 * g + 5]) << 16);
        unsigned int Du = (unsigned)f2bf(p[8 * g + 6]) | ((unsigned)f2bf(p[8 * g + 7]) << 16);
        int s0 = (lg & 1) * 2;
        int src0 = lr + 16 * s0, src1 = src0 + 16;
        bool hi = lg >= 2;
        int a0 = __shfl((int)Au, src0), c0 = __shfl((int)Cu, src0);
        int b0 = __shfl((int)Bu, src0), d0 = __shfl((int)Du, src0);
        int a1 = __shfl((int)Au, src1), c1 = __shfl((int)Cu, src1);
        int b1 = __shfl((int)Bu, src1), d1 = __shfl((int)Du, src1);
        bfrag[g][0] = hi ? (unsigned)c0 : (unsigned)a0;
        bfrag[g][1] = hi ? (unsigned)d0 : (unsigned)b0;
        bfrag[g][2] = hi ? (unsigned)c1 : (unsigned)a1;
        bfrag[g][3] = hi ? (unsigned)d1 : (unsigned)b1;
      }

      __builtin_amdgcn_s_setprio(1);
#pragma unroll
      for (int g = 0; g < 2; ++g)
#pragma unroll
        for (int dt = 0; dt < 8; ++dt) {
          int d = dt * 16 + lr;
          int elem = d * 64 + (((4 * g + lg) ^ (lr & 7)) * 8);
          bf16x8 vf = *reinterpret_cast<const bf16x8*>(&sV[cur][elem]);
          ao[dt] = __builtin_amdgcn_mfma_f32_16x16x32_bf16(
              vf, *reinterpret_cast<const bf16x8*>(&bfrag[g]), ao[dt], 0, 0, 0);
        }
      __builtin_amdgcn_s_setprio(0);
    }

    __syncthreads();
    cur ^= 1;
  }

  float inv = 1.0f / lrun;
  int qrow = qw + lr;
#pragma unroll
  for (int dt = 0; dt < 8; ++dt) {
    u16x4 o4;
#pragma unroll
    for (int r = 0; r < 4; ++r) o4[r] = f2bf(ao[dt][r] * inv);
    *reinterpret_cast<u16x4*>(&O[(size_t)qrow * HID + h * HD + dt * 16 + lg * 4]) = o4;
  }
}

// ---------------- launch ----------------
extern "C" void kernel_launch(void* const* d_in, const int* in_sizes, int n_in,
                              void* d_out, int out_size, void* d_ws, size_t ws_size,
                              hipStream_t stream) {
  const float* hs = (const float*)d_in[0];
  // d_in[1] = position_ids (arange, unused: positions derived from row index)
  const float* Wq = (const float*)d_in[2];
  const float* Wk = (const float*)d_in[3];
  const float* Wv = (const float*)d_in[4];
  const float* Wo = (const float*)d_in[5];

  unsigned short* ws = (unsigned short*)d_ws;
  size_t off = 0;
  unsigned short* H16  = ws + off; off += (size_t)S_LEN * HID;     // also attn-out
  unsigned short* Wcat = ws + off; off += (size_t)NQKV * HID;      // Wq|Wk|Wv, later Wo in rows 0..4095
  unsigned short* Qb   = ws + off; off += (size_t)S_LEN * HID;
  unsigned short* Kb   = ws + off; off += (size_t)S_LEN * NKV * HD;
  unsigned short* Vt   = ws + off; off += (size_t)S_LEN * NKV * HD;
  float2* tab = (float2*)(ws + off); off += (size_t)S_LEN * 64 * 2 * 2;

  auto cast = [&](const float* src, unsigned short* dst, size_t n) {
    int n4 = (int)(n / 4);
    cast_f32_bf16<<<(n4 + 255) / 256, 256, 0, stream>>>(src, dst, n4);
  };

  rope_table<<<(S_LEN * 64 + 255) / 256, 256, 0, stream>>>(tab);
  cast(hs, H16, (size_t)S_LEN * HID);
  cast(Wq, Wcat, (size_t)HID * HID);
  cast(Wk, Wcat + (size_t)HID * HID, (size_t)NKV * HD * HID);
  cast(Wv, Wcat + (size_t)(HID + NKV * HD) * HID, (size_t)NKV * HD * HID);

  // fused QKV projection, 256^2 8-phase, flat grid + XCD-chunked mapping
  gemm_qkv256<<<dim3((NQKV / 256) * (S_LEN / 256)), 512, 0, stream>>>(
      H16, Wcat, Qb, Kb, Vt);

  // Wo cast reuses Wcat rows 0..4095 (stream-ordered after QKV GEMM)
  cast(Wo, Wcat, (size_t)HID * HID);

  // RoPE on Q and K
  {
    int totq = S_LEN * NH * 64;
    rope_kernel<<<(totq + 255) / 256, 256, 0, stream>>>(Qb, tab, NH, totq);
    int totk = S_LEN * NKV * 64;
    rope_kernel<<<(totk + 255) / 256, 256, 0, stream>>>(Kb, tab, NKV, totk);
  }

  // attention -> H16
  attn_kernel<<<dim3(S_LEN / 128, NH), 512, 0, stream>>>(Qb, Kb, Vt, H16);

  // output projection -> fp32 d_out
  gemm_bt<<<dim3(HID / 128, S_LEN / 128), 256, 0, stream>>>(
      H16, Wcat, (float*)d_out, S_LEN, HID, HID);
}

// Round 6
// 400.746 us; speedup vs baseline: 1.0113x; 1.0113x over previous
//
#include <hip/hip_runtime.h>

typedef __attribute__((ext_vector_type(4))) float f32x4;
typedef __attribute__((ext_vector_type(8))) __bf16 bf16x8;
typedef __attribute__((ext_vector_type(4))) unsigned short u16x4;

#define DEVI static __device__ __forceinline__
#define AS1 __attribute__((address_space(1)))
#define AS3 __attribute__((address_space(3)))

static constexpr int S_LEN = 2048;
static constexpr int HID   = 4096;
static constexpr int NH    = 32;
static constexpr int NKV   = 8;
static constexpr int HD    = 128;
static constexpr int NQKV  = HID + 2 * NKV * HD;   // 6144

DEVI unsigned short f2bf(float f) {
  unsigned int u = __float_as_uint(f);
  u += 0x7FFFu + ((u >> 16) & 1u);
  return (unsigned short)(u >> 16);
}
DEVI float bf2f(unsigned short h) {
  return __uint_as_float(((unsigned int)h) << 16);
}

// ---------------- fp32 -> bf16 cast (float4 vectorized) ----------------
__global__ void cast_f32_bf16(const float* __restrict__ in,
                              unsigned short* __restrict__ out, int n4) {
  int i = blockIdx.x * 256 + threadIdx.x;
  if (i >= n4) return;
  float4 v = reinterpret_cast<const float4*>(in)[i];
  u16x4 o;
  o[0] = f2bf(v.x); o[1] = f2bf(v.y); o[2] = f2bf(v.z); o[3] = f2bf(v.w);
  reinterpret_cast<u16x4*>(out)[i] = o;
}

// ---------------- RoPE cos/sin table [S][64] float2 ----------------
__global__ void rope_table(float2* __restrict__ tab) {
  int i = blockIdx.x * 256 + threadIdx.x;
  if (i >= S_LEN * 64) return;
  int j = i & 63, s = i >> 6;
  float inv = powf(10000.0f, -(float)j / 64.0f);
  float ang = (float)s * inv;
  tab[i] = make_float2(cosf(ang), sinf(ang));
}

// ---------------- RoPE in place on bf16 [S][Hn*128] ----------------
__global__ void rope_kernel(unsigned short* __restrict__ X,
                            const float2* __restrict__ tab, int Hn, int total) {
  int i = blockIdx.x * 256 + threadIdx.x;
  if (i >= total) return;
  int j = i & 63;              // freq index 0..63
  int h = (i >> 6) % Hn;
  int s = i / (64 * Hn);
  float2 cs = tab[s * 64 + j];
  unsigned short* p = X + (size_t)s * Hn * HD + h * HD;
  float x1 = bf2f(p[j]);
  float x2 = bf2f(p[j + 64]);
  p[j]      = f2bf(x1 * cs.x - x2 * cs.y);
  p[j + 64] = f2bf(x2 * cs.x + x1 * cs.y);
}

// ============ fused QKV GEMM, 256x256 tile, BK=64, 8-wave, 8-phase ============
// C[2048 x 6144] = H @ Wcat^T. Epilogue routes by block col: Q / K / V^T.
//
// r6 fixes vs r5 (LDS-pipe arithmetic: 8 reads/wave/phase = 256cy floor >
// 155cy MFMA -> LDS-bound; and vmcnt protocol was off-by-one cross-wave):
//  - B-frag register reuse: B(kh) LDS-read once per K-tile (P1,P2), reused
//    from bgr[kh] at P3,P4. 24 ds_reads/K-tile (was 32).
//  - vmcnt BEFORE the mid-phase barrier: wave's vmcnt covering stage p-3
//    precedes a barrier that precedes the phase-(p+1) reads -> cross-wave
//    guarantee holds (stage->read distance is 4 phases everywhere).
//  - sched_barrier(0) after ds_reads pins them above the barrier.
//  - 2D grid (bx fastest) restored; XCD remap regressed FETCH 92->208 MB.
// Peel epilogue drains vmcnt 4 -> 2 -> 0 (P4,P5,P6), traced:
//  entering peel: outstanding={i30P6,i30P7,i30P8}; P1..P3 stage+retire those;
//  P4 vmcnt(4) retires peelP1 (read P5), P5 vmcnt(2) retires peelP2 (read P6),
//  P6 vmcnt(0) retires peelP3 (read P7).
__global__ __launch_bounds__(512, 2) void gemm_qkv256(
    const unsigned short* __restrict__ A,   // [2048][4096]
    const unsigned short* __restrict__ B,   // [6144][4096]
    unsigned short* __restrict__ Qb,
    unsigned short* __restrict__ Kb,
    unsigned short* __restrict__ Vt) {
  __shared__ __align__(16) unsigned short lds[2][32768];
  const int tid = threadIdx.x;
  const int lane = tid & 63, w = tid >> 6;
  const int wm = w >> 2, wn = w & 3;
  const int lr = lane & 15, lg = lane >> 4;
  const int bx = blockIdx.x, by = blockIdx.y;
  const int m0 = by * 256, n0 = bx * 256;
  const int Kd = HID;

  const int sAr = tid >> 3, sAp = tid & 7;   // A stage: row-in-band, phys chunk
  const int sBn = tid >> 2, sBp = tid & 3;   // B stage: row-in-half, phys chunk
  auto stageA = [&](int buf, int t, int band) {
    int row = band * 64 + sAr;
    __builtin_amdgcn_global_load_lds(
        (const AS1 void*)(A + (size_t)(m0 + row) * Kd + t * 64 + ((sAp ^ (row & 7)) * 8)),
        (AS3 void*)(&lds[buf][row * 64 + sAp * 8]), 16, 0, 0);
  };
  auto stageB = [&](int buf, int t, int kh, int hb) {
    int n = hb * 128 + sBn;
    __builtin_amdgcn_global_load_lds(
        (const AS1 void*)(B + (size_t)(n0 + n) * Kd + t * 64 + kh * 32 + ((sBp ^ ((n >> 1) & 3)) * 8)),
        (AS3 void*)(&lds[buf][16384 + kh * 8192 + n * 32 + sBp * 8]), 16, 0, 0);
  };

  // ds_read element offsets (row&7 == lr&7, (n>>1)&3 == (lr>>1)&3)
  const int aoff0 = (wm * 128 + lr) * 64 + ((lg ^ (lr & 7)) * 8);        // kh=0
  const int aoff1 = (wm * 128 + lr) * 64 + (((4 + lg) ^ (lr & 7)) * 8);  // kh=1
  const int boff  = 16384 + (wn * 64 + lr) * 32 + ((lg ^ ((lr >> 1) & 3)) * 8);

  f32x4 acc[8][4] = {};
  bf16x8 bgr[2][4];   // B fragments held across phases (kh0 / kh1)

  // prologue: fully stage tiles 0 (buf0) and 1 (buf1)
#pragma unroll
  for (int b = 0; b < 4; ++b) { stageA(0, 0, b); stageA(1, 1, b); }
#pragma unroll
  for (int kh = 0; kh < 2; ++kh)
#pragma unroll
    for (int hb = 0; hb < 2; ++hb) { stageB(0, 0, kh, hb); stageB(1, 1, kh, hb); }
  asm volatile("s_waitcnt vmcnt(0)" ::: "memory");
  __builtin_amdgcn_s_barrier();

#define PHASE(BUF, MH, KH, LOADB, WAIT, ...)                                   \
  do {                                                                         \
    const unsigned short* ab = &lds[BUF][((KH) ? aoff1 : aoff0) + (MH) * 4096];\
    bf16x8 af0 = *reinterpret_cast<const bf16x8*>(ab);                         \
    bf16x8 af1 = *reinterpret_cast<const bf16x8*>(ab + 1024);                  \
    bf16x8 af2 = *reinterpret_cast<const bf16x8*>(ab + 2048);                  \
    bf16x8 af3 = *reinterpret_cast<const bf16x8*>(ab + 3072);                  \
    if (LOADB) {                                                               \
      const unsigned short* bb = &lds[BUF][boff + (KH) * 8192];                \
      bgr[KH][0] = *reinterpret_cast<const bf16x8*>(bb);                       \
      bgr[KH][1] = *reinterpret_cast<const bf16x8*>(bb + 512);                 \
      bgr[KH][2] = *reinterpret_cast<const bf16x8*>(bb + 1024);                \
      bgr[KH][3] = *reinterpret_cast<const bf16x8*>(bb + 1536);                \
    }                                                                          \
    __builtin_amdgcn_sched_barrier(0);                                         \
    __VA_ARGS__                                                                \
    asm volatile("s_waitcnt vmcnt(" WAIT ")" ::: "memory");                    \
    __builtin_amdgcn_s_barrier();                                              \
    asm volatile("s_waitcnt lgkmcnt(0)" ::: "memory");                         \
    __builtin_amdgcn_sched_barrier(0);                                         \
    __builtin_amdgcn_s_setprio(1);                                             \
    acc[(MH)*4+0][0] = __builtin_amdgcn_mfma_f32_16x16x32_bf16(af0, bgr[KH][0], acc[(MH)*4+0][0],0,0,0); \
    acc[(MH)*4+0][1] = __builtin_amdgcn_mfma_f32_16x16x32_bf16(af0, bgr[KH][1], acc[(MH)*4+0][1],0,0,0); \
    acc[(MH)*4+0][2] = __builtin_amdgcn_mfma_f32_16x16x32_bf16(af0, bgr[KH][2], acc[(MH)*4+0][2],0,0,0); \
    acc[(MH)*4+0][3] = __builtin_amdgcn_mfma_f32_16x16x32_bf16(af0, bgr[KH][3], acc[(MH)*4+0][3],0,0,0); \
    acc[(MH)*4+1][0] = __builtin_amdgcn_mfma_f32_16x16x32_bf16(af1, bgr[KH][0], acc[(MH)*4+1][0],0,0,0); \
    acc[(MH)*4+1][1] = __builtin_amdgcn_mfma_f32_16x16x32_bf16(af1, bgr[KH][1], acc[(MH)*4+1][1],0,0,0); \
    acc[(MH)*4+1][2] = __builtin_amdgcn_mfma_f32_16x16x32_bf16(af1, bgr[KH][2], acc[(MH)*4+1][2],0,0,0); \
    acc[(MH)*4+1][3] = __builtin_amdgcn_mfma_f32_16x16x32_bf16(af1, bgr[KH][3], acc[(MH)*4+1][3],0,0,0); \
    acc[(MH)*4+2][0] = __builtin_amdgcn_mfma_f32_16x16x32_bf16(af2, bgr[KH][0], acc[(MH)*4+2][0],0,0,0); \
    acc[(MH)*4+2][1] = __builtin_amdgcn_mfma_f32_16x16x32_bf16(af2, bgr[KH][1], acc[(MH)*4+2][1],0,0,0); \
    acc[(MH)*4+2][2] = __builtin_amdgcn_mfma_f32_16x16x32_bf16(af2, bgr[KH][2], acc[(MH)*4+2][2],0,0,0); \
    acc[(MH)*4+2][3] = __builtin_amdgcn_mfma_f32_16x16x32_bf16(af2, bgr[KH][3], acc[(MH)*4+2][3],0,0,0); \
    acc[(MH)*4+3][0] = __builtin_amdgcn_mfma_f32_16x16x32_bf16(af3, bgr[KH][0], acc[(MH)*4+3][0],0,0,0); \
    acc[(MH)*4+3][1] = __builtin_amdgcn_mfma_f32_16x16x32_bf16(af3, bgr[KH][1], acc[(MH)*4+3][1],0,0,0); \
    acc[(MH)*4+3][2] = __builtin_amdgcn_mfma_f32_16x16x32_bf16(af3, bgr[KH][2], acc[(MH)*4+3][2],0,0,0); \
    acc[(MH)*4+3][3] = __builtin_amdgcn_mfma_f32_16x16x32_bf16(af3, bgr[KH][3], acc[(MH)*4+3][3],0,0,0); \
    __builtin_amdgcn_s_setprio(0);                                             \
    __builtin_amdgcn_s_barrier();                                              \
  } while (0)

  for (int i = 0; i < 31; ++i) {
    const int t = 2 * i;
    const bool nf = (i != 0);
    PHASE(0, 0, 0, 1, "6", if (nf) { stageB(1, t + 1, 0, 0); stageB(1, t + 1, 0, 1); });
    PHASE(0, 0, 1, 1, "6", if (nf) { stageB(1, t + 1, 1, 0); stageB(1, t + 1, 1, 1); });
    PHASE(0, 1, 0, 0, "6", if (nf) { stageA(1, t + 1, 1); stageA(1, t + 1, 3); });
    PHASE(0, 1, 1, 0, "6", { stageB(0, t + 2, 0, 0); stageB(0, t + 2, 0, 1); });
    PHASE(1, 0, 0, 1, "6", { stageA(0, t + 2, 0); stageA(0, t + 2, 2); });
    PHASE(1, 0, 1, 1, "6", { stageB(0, t + 2, 1, 0); stageB(0, t + 2, 1, 1); });
    PHASE(1, 1, 0, 0, "6", { stageA(0, t + 2, 1); stageA(0, t + 2, 3); });
    PHASE(1, 1, 1, 0, "6", { stageA(1, t + 3, 0); stageA(1, t + 3, 2); });
  }
  {  // peeled last iteration (t=62): stages only P1-P3; drain 4 -> 2 -> 0
    const int t = 62;
    PHASE(0, 0, 0, 1, "6", { stageB(1, t + 1, 0, 0); stageB(1, t + 1, 0, 1); });
    PHASE(0, 0, 1, 1, "6", { stageB(1, t + 1, 1, 0); stageB(1, t + 1, 1, 1); });
    PHASE(0, 1, 0, 0, "6", { stageA(1, t + 1, 1); stageA(1, t + 1, 3); });
    PHASE(0, 1, 1, 0, "4", ;);
    PHASE(1, 0, 0, 1, "2", ;);
    PHASE(1, 0, 1, 1, "0", ;);
    PHASE(1, 1, 0, 0, "0", ;);
    PHASE(1, 1, 1, 0, "0", ;);
  }
#undef PHASE

  // epilogue: route by block col region (bx<16: Q, <20: K, else V transposed)
#pragma unroll
  for (int ar = 0; ar < 8; ++ar) {
#pragma unroll
    for (int fc = 0; fc < 4; ++fc) {
      const int gcol = n0 + wn * 64 + fc * 16 + lr;
      const int growb = m0 + wm * 128 + (ar >> 2) * 64 + (ar & 3) * 16 + lg * 4;
      if (bx < 16) {
#pragma unroll
        for (int rr = 0; rr < 4; ++rr)
          Qb[(size_t)(growb + rr) * HID + gcol] = f2bf(acc[ar][fc][rr]);
      } else if (bx < 20) {
#pragma unroll
        for (int rr = 0; rr < 4; ++rr)
          Kb[(size_t)(growb + rr) * (NKV * HD) + (gcol - HID)] = f2bf(acc[ar][fc][rr]);
      } else {
        u16x4 o4;
#pragma unroll
        for (int rr = 0; rr < 4; ++rr) o4[rr] = f2bf(acc[ar][fc][rr]);
        *reinterpret_cast<u16x4*>(
            &Vt[(size_t)(gcol - HID - NKV * HD) * S_LEN + growb]) = o4;
      }
    }
  }
}

// ---------------- bf16 GEMM: C = A @ B^T (O-projection, fp32 out, m97) ----------------
__global__ __launch_bounds__(256) void gemm_bt(
    const unsigned short* __restrict__ A,
    const unsigned short* __restrict__ B,
    float* __restrict__ C, int M, int N, int Kd) {
  __shared__ __align__(16) unsigned short sA[128 * 32];
  __shared__ __align__(16) unsigned short sB[128 * 32];
  const int tid = threadIdx.x;
  const int lane = tid & 63, w = tid >> 6;
  const int wr = w >> 1, wc = w & 1;
  const int lr = lane & 15, lg = lane >> 4;
  const int m0 = blockIdx.y * 128, n0 = blockIdx.x * 128;

  f32x4 acc[4][4] = {};

  for (int k0 = 0; k0 < Kd; k0 += 32) {
#pragma unroll
    for (int r = 0; r < 2; ++r) {
      int e = (tid + r * 256) * 8;
      int row = e >> 5, col = e & 31;
      __builtin_amdgcn_global_load_lds(
          (const AS1 void*)(A + (size_t)(m0 + row) * Kd + k0 + col),
          (AS3 void*)(sA + e), 16, 0, 0);
      __builtin_amdgcn_global_load_lds(
          (const AS1 void*)(B + (size_t)(n0 + row) * Kd + k0 + col),
          (AS3 void*)(sB + e), 16, 0, 0);
    }
    __syncthreads();

    bf16x8 af[4], bfr[4];
#pragma unroll
    for (int m = 0; m < 4; ++m)
      af[m] = *reinterpret_cast<const bf16x8*>(&sA[(wr * 64 + m * 16 + lr) * 32 + lg * 8]);
#pragma unroll
    for (int n = 0; n < 4; ++n)
      bfr[n] = *reinterpret_cast<const bf16x8*>(&sB[(wc * 64 + n * 16 + lr) * 32 + lg * 8]);
#pragma unroll
    for (int m = 0; m < 4; ++m)
#pragma unroll
      for (int n = 0; n < 4; ++n)
        acc[m][n] = __builtin_amdgcn_mfma_f32_16x16x32_bf16(af[m], bfr[n], acc[m][n], 0, 0, 0);
    __syncthreads();
  }

#pragma unroll
  for (int m = 0; m < 4; ++m)
#pragma unroll
    for (int n = 0; n < 4; ++n) {
      int gcol = n0 + wc * 64 + n * 16 + lr;
#pragma unroll
      for (int r = 0; r < 4; ++r) {
        int grow = m0 + wr * 64 + m * 16 + lg * 4 + r;
        C[(size_t)grow * N + gcol] = acc[m][n][r];
      }
    }
}

// ---------------- causal GQA flash attention, swapped-QK^T, 8-wave ----------------
__global__ __launch_bounds__(512, 4) void attn_kernel(
    const unsigned short* __restrict__ Q,   // [S][NH*HD]
    const unsigned short* __restrict__ Kb,  // [S][NKV*HD]
    const unsigned short* __restrict__ Vt,  // [NKV*HD][S]
    unsigned short* __restrict__ O) {       // [S][NH*HD]
  __shared__ __align__(16) unsigned short sK[2][64 * 128];
  __shared__ __align__(16) unsigned short sV[2][128 * 64];
  const int tid = threadIdx.x;
  const int lane = tid & 63, w = tid >> 6;
  const int lr = lane & 15, lg = lane >> 4;
  const int qt = (int)gridDim.x - 1 - (int)blockIdx.x;  // descending work order
  const int h = blockIdx.y, kvh = h >> 2;
  const int q0 = qt * 128, qw = q0 + w * 16;
  const int KVS = NKV * HD;

  bf16x8 qf[4];
#pragma unroll
  for (int ks = 0; ks < 4; ++ks)
    qf[ks] = *reinterpret_cast<const bf16x8*>(
        &Q[(size_t)(qw + lr) * HID + h * HD + ks * 32 + lg * 8]);

  f32x4 ao[8] = {};
  float mrun = -INFINITY, lrun = 0.f;   // mrun in log2 units
  const float S2 = 0.12751745f;         // (1/sqrt(128)) * log2(e)
  const int ntiles = 2 * qt + 2;

  auto stage = [&](int b, int kv0) {
#pragma unroll
    for (int i = 0; i < 2; ++i) {
      int off = (tid + i * 512) * 8;
      int r = off >> 7, c = (off >> 3) & 15;
      __builtin_amdgcn_global_load_lds(
          (const AS1 void*)(Kb + (size_t)(kv0 + r) * KVS + kvh * HD + ((c ^ (r & 15)) * 8)),
          (AS3 void*)(&sK[b][off]), 16, 0, 0);
    }
#pragma unroll
    for (int i = 0; i < 2; ++i) {
      int off = (tid + i * 512) * 8;
      int r = off >> 6, c = (off >> 3) & 7;
      __builtin_amdgcn_global_load_lds(
          (const AS1 void*)(Vt + (size_t)(kvh * HD + r) * S_LEN + kv0 + ((c ^ (r & 7)) * 8)),
          (AS3 void*)(&sV[b][off]), 16, 0, 0);
    }
  };

  stage(0, 0);
  __syncthreads();
  int cur = 0;

  for (int t = 0; t < ntiles; ++t) {
    const int kv0 = t * 64;
    if (t + 1 < ntiles) stage(cur ^ 1, kv0 + 64);

    if (kv0 <= qw + 15) {
      f32x4 sacc[4] = {};
      __builtin_amdgcn_s_setprio(1);
#pragma unroll
      for (int kt = 0; kt < 4; ++kt)
#pragma unroll
        for (int ks = 0; ks < 4; ++ks) {
          int elem = (kt * 16 + lr) * 128 + (((4 * ks + lg) ^ lr) * 8);
          bf16x8 kf = *reinterpret_cast<const bf16x8*>(&sK[cur][elem]);
          sacc[kt] = __builtin_amdgcn_mfma_f32_16x16x32_bf16(kf, qf[ks], sacc[kt], 0, 0, 0);
        }
      __builtin_amdgcn_s_setprio(0);

      const bool needMask = (kv0 + 63 > qw);
      const int qg = qw + lr;
      float p[16];
      float tmax = -INFINITY;
#pragma unroll
      for (int kt = 0; kt < 4; ++kt)
#pragma unroll
        for (int r = 0; r < 4; ++r) {
          float v = sacc[kt][r] * S2;
          if (needMask && (kv0 + kt * 16 + lg * 4 + r > qg)) v = -INFINITY;
          p[kt * 4 + r] = v;
          tmax = fmaxf(tmax, v);
        }
      tmax = fmaxf(tmax, __shfl_xor(tmax, 16));
      tmax = fmaxf(tmax, __shfl_xor(tmax, 32));
      // T13 defer-max: only rescale when max grew past threshold (log2 units)
      if (!__all(tmax <= mrun + 8.0f)) {
        float mnew = fmaxf(mrun, tmax);
        float corr = exp2f(mrun - mnew);
        lrun *= corr;
#pragma unroll
        for (int dt = 0; dt < 8; ++dt) ao[dt] *= corr;
        mrun = mnew;
      }
      float rs = 0.f;
#pragma unroll
      for (int i = 0; i < 16; ++i) { p[i] = exp2f(p[i] - mrun); rs += p[i]; }
      rs += __shfl_xor(rs, 16);
      rs += __shfl_xor(rs, 32);
      lrun += rs;

      unsigned int bfrag[2][4];
#pragma unroll
      for (int g = 0; g < 2; ++g) {
        unsigned int Au = (unsigned)f2bf(p[8 * g + 0]) | ((unsigned)f2bf(p[8 * g + 1]) << 16);
        unsigned int Bu = (unsigned)f2bf(p[8 * g + 2]) | ((unsigned)f2bf(p[8 * g + 3]) << 16);
        unsigned int Cu = (unsigned)f2bf(p[8 * g + 4]) | ((unsigned)f2bf(p[8 * g + 5]) << 16);
        unsigned int Du = (unsigned)f2bf(p[8 * g + 6]) | ((unsigned)f2bf(p[8 * g + 7]) << 16);
        int s0 = (lg & 1) * 2;
        int src0 = lr + 16 * s0, src1 = src0 + 16;
        bool hi = lg >= 2;
        int a0 = __shfl((int)Au, src0), c0 = __shfl((int)Cu, src0);
        int b0 = __shfl((int)Bu, src0), d0 = __shfl((int)Du, src0);
        int a1 = __shfl((int)Au, src1), c1 = __shfl((int)Cu, src1);
        int b1 = __shfl((int)Bu, src1), d1 = __shfl((int)Du, src1);
        bfrag[g][0] = hi ? (unsigned)c0 : (unsigned)a0;
        bfrag[g][1] = hi ? (unsigned)d0 : (unsigned)b0;
        bfrag[g][2] = hi ? (unsigned)c1 : (unsigned)a1;
        bfrag[g][3] = hi ? (unsigned)d1 : (unsigned)b1;
      }

      __builtin_amdgcn_s_setprio(1);
#pragma unroll
      for (int g = 0; g < 2; ++g)
#pragma unroll
        for (int dt = 0; dt < 8; ++dt) {
          int d = dt * 16 + lr;
          int elem = d * 64 + (((4 * g + lg) ^ (lr & 7)) * 8);
          bf16x8 vf = *reinterpret_cast<const bf16x8*>(&sV[cur][elem]);
          ao[dt] = __builtin_amdgcn_mfma_f32_16x16x32_bf16(
              vf, *reinterpret_cast<const bf16x8*>(&bfrag[g]), ao[dt], 0, 0, 0);
        }
      __builtin_amdgcn_s_setprio(0);
    }

    __syncthreads();
    cur ^= 1;
  }

  float inv = 1.0f / lrun;
  int qrow = qw + lr;
#pragma unroll
  for (int dt = 0; dt < 8; ++dt) {
    u16x4 o4;
#pragma unroll
    for (int r = 0; r < 4; ++r) o4[r] = f2bf(ao[dt][r] * inv);
    *reinterpret_cast<u16x4*>(&O[(size_t)qrow * HID + h * HD + dt * 16 + lg * 4]) = o4;
  }
}

// ---------------- launch ----------------
extern "C" void kernel_launch(void* const* d_in, const int* in_sizes, int n_in,
                              void* d_out, int out_size, void* d_ws, size_t ws_size,
                              hipStream_t stream) {
  const float* hs = (const float*)d_in[0];
  // d_in[1] = position_ids (arange, unused: positions derived from row index)
  const float* Wq = (const float*)d_in[2];
  const float* Wk = (const float*)d_in[3];
  const float* Wv = (const float*)d_in[4];
  const float* Wo = (const float*)d_in[5];

  unsigned short* ws = (unsigned short*)d_ws;
  size_t off = 0;
  unsigned short* H16  = ws + off; off += (size_t)S_LEN * HID;     // also attn-out
  unsigned short* Wcat = ws + off; off += (size_t)NQKV * HID;      // Wq|Wk|Wv, later Wo in rows 0..4095
  unsigned short* Qb   = ws + off; off += (size_t)S_LEN * HID;
  unsigned short* Kb   = ws + off; off += (size_t)S_LEN * NKV * HD;
  unsigned short* Vt   = ws + off; off += (size_t)S_LEN * NKV * HD;
  float2* tab = (float2*)(ws + off); off += (size_t)S_LEN * 64 * 2 * 2;

  auto cast = [&](const float* src, unsigned short* dst, size_t n) {
    int n4 = (int)(n / 4);
    cast_f32_bf16<<<(n4 + 255) / 256, 256, 0, stream>>>(src, dst, n4);
  };

  rope_table<<<(S_LEN * 64 + 255) / 256, 256, 0, stream>>>(tab);
  cast(hs, H16, (size_t)S_LEN * HID);
  cast(Wq, Wcat, (size_t)HID * HID);
  cast(Wk, Wcat + (size_t)HID * HID, (size_t)NKV * HD * HID);
  cast(Wv, Wcat + (size_t)(HID + NKV * HD) * HID, (size_t)NKV * HD * HID);

  // fused QKV projection, 256^2 8-phase (V written transposed)
  gemm_qkv256<<<dim3(NQKV / 256, S_LEN / 256), 512, 0, stream>>>(
      H16, Wcat, Qb, Kb, Vt);

  // Wo cast reuses Wcat rows 0..4095 (stream-ordered after QKV GEMM)
  cast(Wo, Wcat, (size_t)HID * HID);

  // RoPE on Q and K
  {
    int totq = S_LEN * NH * 64;
    rope_kernel<<<(totq + 255) / 256, 256, 0, stream>>>(Qb, tab, NH, totq);
    int totk = S_LEN * NKV * 64;
    rope_kernel<<<(totk + 255) / 256, 256, 0, stream>>>(Kb, tab, NKV, totk);
  }

  // attention -> H16
  attn_kernel<<<dim3(S_LEN / 128, NH), 512, 0, stream>>>(Qb, Kb, Vt, H16);

  // output projection -> fp32 d_out
  gemm_bt<<<dim3(HID / 128, S_LEN / 128), 256, 0, stream>>>(
      H16, Wcat, (float*)d_out, S_LEN, HID, HID);
}

// Round 7
// 360.135 us; speedup vs baseline: 1.1254x; 1.1128x over previous
//
#include <hip/hip_runtime.h>

typedef __attribute__((ext_vector_type(4))) float f32x4;
typedef __attribute__((ext_vector_type(8))) __bf16 bf16x8;
typedef __attribute__((ext_vector_type(4))) unsigned short u16x4;

#define DEVI static __device__ __forceinline__
#define AS1 __attribute__((address_space(1)))
#define AS3 __attribute__((address_space(3)))

static constexpr int S_LEN = 2048;
static constexpr int HID   = 4096;
static constexpr int NH    = 32;
static constexpr int NKV   = 8;
static constexpr int HD    = 128;
static constexpr int NQKV  = HID + 2 * NKV * HD;   // 6144

DEVI unsigned short f2bf(float f) {
  unsigned int u = __float_as_uint(f);
  u += 0x7FFFu + ((u >> 16) & 1u);
  return (unsigned short)(u >> 16);
}
DEVI float bf2f(unsigned short h) {
  return __uint_as_float(((unsigned int)h) << 16);
}

// ---------------- fp32 -> bf16 cast (float4 vectorized) ----------------
__global__ void cast_f32_bf16(const float* __restrict__ in,
                              unsigned short* __restrict__ out, int n4) {
  int i = blockIdx.x * 256 + threadIdx.x;
  if (i >= n4) return;
  float4 v = reinterpret_cast<const float4*>(in)[i];
  u16x4 o;
  o[0] = f2bf(v.x); o[1] = f2bf(v.y); o[2] = f2bf(v.z); o[3] = f2bf(v.w);
  reinterpret_cast<u16x4*>(out)[i] = o;
}

// ---------------- RoPE cos/sin table [S][64] float2 ----------------
__global__ void rope_table(float2* __restrict__ tab) {
  int i = blockIdx.x * 256 + threadIdx.x;
  if (i >= S_LEN * 64) return;
  int j = i & 63, s = i >> 6;
  float inv = powf(10000.0f, -(float)j / 64.0f);
  float ang = (float)s * inv;
  tab[i] = make_float2(cosf(ang), sinf(ang));
}

// ---------------- RoPE in place on bf16 Q and K (one launch) ----------------
__global__ void rope_all(unsigned short* __restrict__ Qb,
                         unsigned short* __restrict__ Kb,
                         const float2* __restrict__ tab) {
  const int totq = S_LEN * NH * 64;
  const int tot  = totq + S_LEN * NKV * 64;
  int i = blockIdx.x * 256 + threadIdx.x;
  if (i >= tot) return;
  unsigned short* X; int Hn, idx;
  if (i < totq) { X = Qb; Hn = NH; idx = i; }
  else          { X = Kb; Hn = NKV; idx = i - totq; }
  int j = idx & 63;
  int h = (idx >> 6) % Hn;
  int s = idx / (64 * Hn);
  float2 cs = tab[s * 64 + j];
  unsigned short* p = X + (size_t)s * Hn * HD + h * HD;
  float x1 = bf2f(p[j]);
  float x2 = bf2f(p[j + 64]);
  p[j]      = f2bf(x1 * cs.x - x2 * cs.y);
  p[j + 64] = f2bf(x2 * cs.x + x1 * cs.y);
}

// ============ fused QKV GEMM, 256x256 tile, BK=64, 8-wave, 8-phase ============
// (frozen from r6; see r6 notes)
__global__ __launch_bounds__(512, 2) void gemm_qkv256(
    const unsigned short* __restrict__ A,   // [2048][4096]
    const unsigned short* __restrict__ B,   // [6144][4096]
    unsigned short* __restrict__ Qb,
    unsigned short* __restrict__ Kb,
    unsigned short* __restrict__ Vt) {
  __shared__ __align__(16) unsigned short lds[2][32768];
  const int tid = threadIdx.x;
  const int lane = tid & 63, w = tid >> 6;
  const int wm = w >> 2, wn = w & 3;
  const int lr = lane & 15, lg = lane >> 4;
  const int bx = blockIdx.x, by = blockIdx.y;
  const int m0 = by * 256, n0 = bx * 256;
  const int Kd = HID;

  const int sAr = tid >> 3, sAp = tid & 7;
  const int sBn = tid >> 2, sBp = tid & 3;
  auto stageA = [&](int buf, int t, int band) {
    int row = band * 64 + sAr;
    __builtin_amdgcn_global_load_lds(
        (const AS1 void*)(A + (size_t)(m0 + row) * Kd + t * 64 + ((sAp ^ (row & 7)) * 8)),
        (AS3 void*)(&lds[buf][row * 64 + sAp * 8]), 16, 0, 0);
  };
  auto stageB = [&](int buf, int t, int kh, int hb) {
    int n = hb * 128 + sBn;
    __builtin_amdgcn_global_load_lds(
        (const AS1 void*)(B + (size_t)(n0 + n) * Kd + t * 64 + kh * 32 + ((sBp ^ ((n >> 1) & 3)) * 8)),
        (AS3 void*)(&lds[buf][16384 + kh * 8192 + n * 32 + sBp * 8]), 16, 0, 0);
  };

  const int aoff0 = (wm * 128 + lr) * 64 + ((lg ^ (lr & 7)) * 8);
  const int aoff1 = (wm * 128 + lr) * 64 + (((4 + lg) ^ (lr & 7)) * 8);
  const int boff  = 16384 + (wn * 64 + lr) * 32 + ((lg ^ ((lr >> 1) & 3)) * 8);

  f32x4 acc[8][4] = {};
  bf16x8 bgr[2][4];

#pragma unroll
  for (int b = 0; b < 4; ++b) { stageA(0, 0, b); stageA(1, 1, b); }
#pragma unroll
  for (int kh = 0; kh < 2; ++kh)
#pragma unroll
    for (int hb = 0; hb < 2; ++hb) { stageB(0, 0, kh, hb); stageB(1, 1, kh, hb); }
  asm volatile("s_waitcnt vmcnt(0)" ::: "memory");
  __builtin_amdgcn_s_barrier();

#define PHASE(BUF, MH, KH, LOADB, WAIT, ...)                                   \
  do {                                                                         \
    const unsigned short* ab = &lds[BUF][((KH) ? aoff1 : aoff0) + (MH) * 4096];\
    bf16x8 af0 = *reinterpret_cast<const bf16x8*>(ab);                         \
    bf16x8 af1 = *reinterpret_cast<const bf16x8*>(ab + 1024);                  \
    bf16x8 af2 = *reinterpret_cast<const bf16x8*>(ab + 2048);                  \
    bf16x8 af3 = *reinterpret_cast<const bf16x8*>(ab + 3072);                  \
    if (LOADB) {                                                               \
      const unsigned short* bb = &lds[BUF][boff + (KH) * 8192];                \
      bgr[KH][0] = *reinterpret_cast<const bf16x8*>(bb);                       \
      bgr[KH][1] = *reinterpret_cast<const bf16x8*>(bb + 512);                 \
      bgr[KH][2] = *reinterpret_cast<const bf16x8*>(bb + 1024);                \
      bgr[KH][3] = *reinterpret_cast<const bf16x8*>(bb + 1536);                \
    }                                                                          \
    __builtin_amdgcn_sched_barrier(0);                                         \
    __VA_ARGS__                                                                \
    asm volatile("s_waitcnt vmcnt(" WAIT ")" ::: "memory");                    \
    __builtin_amdgcn_s_barrier();                                              \
    asm volatile("s_waitcnt lgkmcnt(0)" ::: "memory");                         \
    __builtin_amdgcn_sched_barrier(0);                                         \
    __builtin_amdgcn_s_setprio(1);                                             \
    acc[(MH)*4+0][0] = __builtin_amdgcn_mfma_f32_16x16x32_bf16(af0, bgr[KH][0], acc[(MH)*4+0][0],0,0,0); \
    acc[(MH)*4+0][1] = __builtin_amdgcn_mfma_f32_16x16x32_bf16(af0, bgr[KH][1], acc[(MH)*4+0][1],0,0,0); \
    acc[(MH)*4+0][2] = __builtin_amdgcn_mfma_f32_16x16x32_bf16(af0, bgr[KH][2], acc[(MH)*4+0][2],0,0,0); \
    acc[(MH)*4+0][3] = __builtin_amdgcn_mfma_f32_16x16x32_bf16(af0, bgr[KH][3], acc[(MH)*4+0][3],0,0,0); \
    acc[(MH)*4+1][0] = __builtin_amdgcn_mfma_f32_16x16x32_bf16(af1, bgr[KH][0], acc[(MH)*4+1][0],0,0,0); \
    acc[(MH)*4+1][1] = __builtin_amdgcn_mfma_f32_16x16x32_bf16(af1, bgr[KH][1], acc[(MH)*4+1][1],0,0,0); \
    acc[(MH)*4+1][2] = __builtin_amdgcn_mfma_f32_16x16x32_bf16(af1, bgr[KH][2], acc[(MH)*4+1][2],0,0,0); \
    acc[(MH)*4+1][3] = __builtin_amdgcn_mfma_f32_16x16x32_bf16(af1, bgr[KH][3], acc[(MH)*4+1][3],0,0,0); \
    acc[(MH)*4+2][0] = __builtin_amdgcn_mfma_f32_16x16x32_bf16(af2, bgr[KH][0], acc[(MH)*4+2][0],0,0,0); \
    acc[(MH)*4+2][1] = __builtin_amdgcn_mfma_f32_16x16x32_bf16(af2, bgr[KH][1], acc[(MH)*4+2][1],0,0,0); \
    acc[(MH)*4+2][2] = __builtin_amdgcn_mfma_f32_16x16x32_bf16(af2, bgr[KH][2], acc[(MH)*4+2][2],0,0,0); \
    acc[(MH)*4+2][3] = __builtin_amdgcn_mfma_f32_16x16x32_bf16(af2, bgr[KH][3], acc[(MH)*4+2][3],0,0,0); \
    acc[(MH)*4+3][0] = __builtin_amdgcn_mfma_f32_16x16x32_bf16(af3, bgr[KH][0], acc[(MH)*4+3][0],0,0,0); \
    acc[(MH)*4+3][1] = __builtin_amdgcn_mfma_f32_16x16x32_bf16(af3, bgr[KH][1], acc[(MH)*4+3][1],0,0,0); \
    acc[(MH)*4+3][2] = __builtin_amdgcn_mfma_f32_16x16x32_bf16(af3, bgr[KH][2], acc[(MH)*4+3][2],0,0,0); \
    acc[(MH)*4+3][3] = __builtin_amdgcn_mfma_f32_16x16x32_bf16(af3, bgr[KH][3], acc[(MH)*4+3][3],0,0,0); \
    __builtin_amdgcn_s_setprio(0);                                             \
    __builtin_amdgcn_s_barrier();                                              \
  } while (0)

  for (int i = 0; i < 31; ++i) {
    const int t = 2 * i;
    const bool nf = (i != 0);
    PHASE(0, 0, 0, 1, "6", if (nf) { stageB(1, t + 1, 0, 0); stageB(1, t + 1, 0, 1); });
    PHASE(0, 0, 1, 1, "6", if (nf) { stageB(1, t + 1, 1, 0); stageB(1, t + 1, 1, 1); });
    PHASE(0, 1, 0, 0, "6", if (nf) { stageA(1, t + 1, 1); stageA(1, t + 1, 3); });
    PHASE(0, 1, 1, 0, "6", { stageB(0, t + 2, 0, 0); stageB(0, t + 2, 0, 1); });
    PHASE(1, 0, 0, 1, "6", { stageA(0, t + 2, 0); stageA(0, t + 2, 2); });
    PHASE(1, 0, 1, 1, "6", { stageB(0, t + 2, 1, 0); stageB(0, t + 2, 1, 1); });
    PHASE(1, 1, 0, 0, "6", { stageA(0, t + 2, 1); stageA(0, t + 2, 3); });
    PHASE(1, 1, 1, 0, "6", { stageA(1, t + 3, 0); stageA(1, t + 3, 2); });
  }
  {
    const int t = 62;
    PHASE(0, 0, 0, 1, "6", { stageB(1, t + 1, 0, 0); stageB(1, t + 1, 0, 1); });
    PHASE(0, 0, 1, 1, "6", { stageB(1, t + 1, 1, 0); stageB(1, t + 1, 1, 1); });
    PHASE(0, 1, 0, 0, "6", { stageA(1, t + 1, 1); stageA(1, t + 1, 3); });
    PHASE(0, 1, 1, 0, "4", ;);
    PHASE(1, 0, 0, 1, "2", ;);
    PHASE(1, 0, 1, 1, "0", ;);
    PHASE(1, 1, 0, 0, "0", ;);
    PHASE(1, 1, 1, 0, "0", ;);
  }
#undef PHASE

#pragma unroll
  for (int ar = 0; ar < 8; ++ar) {
#pragma unroll
    for (int fc = 0; fc < 4; ++fc) {
      const int gcol = n0 + wn * 64 + fc * 16 + lr;
      const int growb = m0 + wm * 128 + (ar >> 2) * 64 + (ar & 3) * 16 + lg * 4;
      if (bx < 16) {
#pragma unroll
        for (int rr = 0; rr < 4; ++rr)
          Qb[(size_t)(growb + rr) * HID + gcol] = f2bf(acc[ar][fc][rr]);
      } else if (bx < 20) {
#pragma unroll
        for (int rr = 0; rr < 4; ++rr)
          Kb[(size_t)(growb + rr) * (NKV * HD) + (gcol - HID)] = f2bf(acc[ar][fc][rr]);
      } else {
        u16x4 o4;
#pragma unroll
        for (int rr = 0; rr < 4; ++rr) o4[rr] = f2bf(acc[ar][fc][rr]);
        *reinterpret_cast<u16x4*>(
            &Vt[(size_t)(gcol - HID - NKV * HD) * S_LEN + growb]) = o4;
      }
    }
  }
}

// ======== O-projection GEMM, 128x256 tile, BK=64, 8-wave, 8-phase ========
// C[2048x4096] fp32 = A(bf16) @ B(bf16)^T. Grid 16x16 = 256 blocks = 1/CU.
// 8 waves as 2M x 4N -> wave tile 64x64 (acc[4][4]); phase = (buf,kh,mh),
// 8 MFMA/phase; B frags read at mh0, register-reused at mh1.
// LDS/buf: A [128][64] (16 KB, 2 stage units) + B [kh][256][32] (32 KB,
// 4 units) = 48 KB; dbuf 96 KB. Swizzles as in QKV (conflict-free, rule 21).
//
// Stage placement (iter computes t=2i @buf0 P1-4, t+1 @buf1 P5-8); every
// region staged strictly after its old tile's last reader (WAR-safe, barrier
// between), distances 4-6 phases:
//   P1: A(b1,t+1) u0,u1 + B(b1,t+1,kh1) hb0,hb1   [reads: P5-P8 / P7]
//   P3: B(b0,t+2,kh0) hb0,hb1                     [read next-P1]
//   P5: A(b0,t+2) u0,u1 + B(b0,t+2,kh1) hb0,hb1   [reads next-P1..P4 / P3]
//   P7: B(b1,t+3,kh0) hb0,hb1                     [read next-iter P5]
// vmcnt protocol (derived queue trace; vmcnt precedes 2 barriers before the
// protected reads -> cross-wave safe): only P4 and P8 block:
//   P4: queue [P7'(2),P1(4),P3(2)]=8, vmcnt(2) retires P7'+P1 (P5's reads)
//   P8: queue [P3(2),P5(4),P7(2)]=8, vmcnt(2) retires P3+P5 (next-P1's reads)
// i==0: P1 skipped (prologue staged t0,t1; P4/P8 vmcnt(2) then no-op/safe).
// Peel i==31: only P1 stages; P4 vmcnt(0) covers P5-P8.
__global__ __launch_bounds__(512, 2) void gemm_o256(
    const unsigned short* __restrict__ A,   // [2048][4096] bf16
    const unsigned short* __restrict__ B,   // [4096][4096] bf16 (Wo)
    float* __restrict__ C) {                // [2048][4096] fp32
  __shared__ __align__(16) unsigned short lds[2][24576];
  const int tid = threadIdx.x;
  const int lane = tid & 63, w = tid >> 6;
  const int wm = w >> 2, wn = w & 3;
  const int lr = lane & 15, lg = lane >> 4;
  const int m0 = blockIdx.y * 128, n0 = blockIdx.x * 256;
  const int Kd = HID;

  const int sAr = tid >> 3, sAp = tid & 7;
  const int sBn = tid >> 2, sBp = tid & 3;
  auto stA = [&](int buf, int t, int unit) {
    int row = unit * 64 + sAr;
    __builtin_amdgcn_global_load_lds(
        (const AS1 void*)(A + (size_t)(m0 + row) * Kd + t * 64 + ((sAp ^ (row & 7)) * 8)),
        (AS3 void*)(&lds[buf][row * 64 + sAp * 8]), 16, 0, 0);
  };
  auto stB = [&](int buf, int t, int kh, int hb) {
    int n = hb * 128 + sBn;
    __builtin_amdgcn_global_load_lds(
        (const AS1 void*)(B + (size_t)(n0 + n) * Kd + t * 64 + kh * 32 + ((sBp ^ ((n >> 1) & 3)) * 8)),
        (AS3 void*)(&lds[buf][8192 + kh * 8192 + n * 32 + sBp * 8]), 16, 0, 0);
  };

  const int aoffk0 = (wm * 64 + lr) * 64 + ((lg ^ (lr & 7)) * 8);
  const int aoffk1 = (wm * 64 + lr) * 64 + (((4 + lg) ^ (lr & 7)) * 8);
  const int boff   = 8192 + (wn * 64 + lr) * 32 + ((lg ^ ((lr >> 1) & 3)) * 8);

  f32x4 acc[4][4] = {};
  bf16x8 bgr[4];

  // prologue: t0 -> buf0, t1 -> buf1 (12 loads)
#pragma unroll
  for (int u = 0; u < 2; ++u) { stA(0, 0, u); stA(1, 1, u); }
#pragma unroll
  for (int kh = 0; kh < 2; ++kh)
#pragma unroll
    for (int hb = 0; hb < 2; ++hb) { stB(0, 0, kh, hb); stB(1, 1, kh, hb); }
  asm volatile("s_waitcnt vmcnt(0)" ::: "memory");
  __builtin_amdgcn_s_barrier();

#define OPHASE(BUF, KH, MH, LOADB, WAITOP, ...)                                \
  do {                                                                         \
    const unsigned short* ab = &lds[BUF][((KH) ? aoffk1 : aoffk0) + (MH) * 2048];\
    bf16x8 af0 = *reinterpret_cast<const bf16x8*>(ab);                         \
    bf16x8 af1 = *reinterpret_cast<const bf16x8*>(ab + 1024);                  \
    if (LOADB) {                                                               \
      const unsigned short* bb = &lds[BUF][boff + (KH) * 8192];                \
      bgr[0] = *reinterpret_cast<const bf16x8*>(bb);                           \
      bgr[1] = *reinterpret_cast<const bf16x8*>(bb + 512);                     \
      bgr[2] = *reinterpret_cast<const bf16x8*>(bb + 1024);                    \
      bgr[3] = *reinterpret_cast<const bf16x8*>(bb + 1536);                    \
    }                                                                          \
    __builtin_amdgcn_sched_barrier(0);                                         \
    __VA_ARGS__                                                                \
    WAITOP                                                                     \
    __builtin_amdgcn_s_barrier();                                              \
    asm volatile("s_waitcnt lgkmcnt(0)" ::: "memory");                         \
    __builtin_amdgcn_sched_barrier(0);                                         \
    __builtin_amdgcn_s_setprio(1);                                             \
    acc[(MH)*2+0][0] = __builtin_amdgcn_mfma_f32_16x16x32_bf16(af0, bgr[0], acc[(MH)*2+0][0],0,0,0); \
    acc[(MH)*2+0][1] = __builtin_amdgcn_mfma_f32_16x16x32_bf16(af0, bgr[1], acc[(MH)*2+0][1],0,0,0); \
    acc[(MH)*2+0][2] = __builtin_amdgcn_mfma_f32_16x16x32_bf16(af0, bgr[2], acc[(MH)*2+0][2],0,0,0); \
    acc[(MH)*2+0][3] = __builtin_amdgcn_mfma_f32_16x16x32_bf16(af0, bgr[3], acc[(MH)*2+0][3],0,0,0); \
    acc[(MH)*2+1][0] = __builtin_amdgcn_mfma_f32_16x16x32_bf16(af1, bgr[0], acc[(MH)*2+1][0],0,0,0); \
    acc[(MH)*2+1][1] = __builtin_amdgcn_mfma_f32_16x16x32_bf16(af1, bgr[1], acc[(MH)*2+1][1],0,0,0); \
    acc[(MH)*2+1][2] = __builtin_amdgcn_mfma_f32_16x16x32_bf16(af1, bgr[2], acc[(MH)*2+1][2],0,0,0); \
    acc[(MH)*2+1][3] = __builtin_amdgcn_mfma_f32_16x16x32_bf16(af1, bgr[3], acc[(MH)*2+1][3],0,0,0); \
    __builtin_amdgcn_s_setprio(0);                                             \
    __builtin_amdgcn_s_barrier();                                              \
  } while (0)

#define VM2 asm volatile("s_waitcnt vmcnt(2)" ::: "memory");
#define VM0 asm volatile("s_waitcnt vmcnt(0)" ::: "memory");
#define NOW

  for (int i = 0; i < 31; ++i) {
    const int t = 2 * i;
    const bool nf = (i != 0);
    OPHASE(0, 0, 0, 1, NOW, if (nf) { stA(1, t + 1, 0); stA(1, t + 1, 1);
                                      stB(1, t + 1, 1, 0); stB(1, t + 1, 1, 1); });
    OPHASE(0, 0, 1, 0, NOW, ;);
    OPHASE(0, 1, 0, 1, NOW, { stB(0, t + 2, 0, 0); stB(0, t + 2, 0, 1); });
    OPHASE(0, 1, 1, 0, VM2, ;);
    OPHASE(1, 0, 0, 1, NOW, { stA(0, t + 2, 0); stA(0, t + 2, 1);
                              stB(0, t + 2, 1, 0); stB(0, t + 2, 1, 1); });
    OPHASE(1, 0, 1, 0, NOW, ;);
    OPHASE(1, 1, 0, 1, NOW, { stB(1, t + 3, 0, 0); stB(1, t + 3, 0, 1); });
    OPHASE(1, 1, 1, 0, VM2, ;);
  }
  {  // peel i = 31 (t=62): only P1 stages; P4 drains everything
    const int t = 62;
    OPHASE(0, 0, 0, 1, NOW, { stA(1, t + 1, 0); stA(1, t + 1, 1);
                              stB(1, t + 1, 1, 0); stB(1, t + 1, 1, 1); });
    OPHASE(0, 0, 1, 0, NOW, ;);
    OPHASE(0, 1, 0, 1, NOW, ;);
    OPHASE(0, 1, 1, 0, VM0, ;);
    OPHASE(1, 0, 0, 1, NOW, ;);
    OPHASE(1, 0, 1, 0, NOW, ;);
    OPHASE(1, 1, 0, 1, NOW, ;);
    OPHASE(1, 1, 1, 0, NOW, ;);
  }
#undef OPHASE
#undef VM2
#undef VM0
#undef NOW

  // epilogue: fp32 C, coalesced over lr
#pragma unroll
  for (int ar = 0; ar < 4; ++ar) {
#pragma unroll
    for (int fc = 0; fc < 4; ++fc) {
      const int gcol = n0 + wn * 64 + fc * 16 + lr;
      const int growb = m0 + wm * 64 + ar * 16 + lg * 4;
#pragma unroll
      for (int rr = 0; rr < 4; ++rr)
        C[(size_t)(growb + rr) * HID + gcol] = acc[ar][fc][rr];
    }
  }
}

// ---------------- causal GQA flash attention, swapped-QK^T, 8-wave ----------------
__global__ __launch_bounds__(512, 4) void attn_kernel(
    const unsigned short* __restrict__ Q,   // [S][NH*HD]
    const unsigned short* __restrict__ Kb,  // [S][NKV*HD]
    const unsigned short* __restrict__ Vt,  // [NKV*HD][S]
    unsigned short* __restrict__ O) {       // [S][NH*HD]
  __shared__ __align__(16) unsigned short sK[2][64 * 128];
  __shared__ __align__(16) unsigned short sV[2][128 * 64];
  const int tid = threadIdx.x;
  const int lane = tid & 63, w = tid >> 6;
  const int lr = lane & 15, lg = lane >> 4;
  const int qt = (int)gridDim.x - 1 - (int)blockIdx.x;
  const int h = blockIdx.y, kvh = h >> 2;
  const int q0 = qt * 128, qw = q0 + w * 16;
  const int KVS = NKV * HD;

  bf16x8 qf[4];
#pragma unroll
  for (int ks = 0; ks < 4; ++ks)
    qf[ks] = *reinterpret_cast<const bf16x8*>(
        &Q[(size_t)(qw + lr) * HID + h * HD + ks * 32 + lg * 8]);

  f32x4 ao[8] = {};
  float mrun = -INFINITY, lrun = 0.f;
  const float S2 = 0.12751745f;  // (1/sqrt(128)) * log2(e)
  const int ntiles = 2 * qt + 2;

  auto stage = [&](int b, int kv0) {
#pragma unroll
    for (int i = 0; i < 2; ++i) {
      int off = (tid + i * 512) * 8;
      int r = off >> 7, c = (off >> 3) & 15;
      __builtin_amdgcn_global_load_lds(
          (const AS1 void*)(Kb + (size_t)(kv0 + r) * KVS + kvh * HD + ((c ^ (r & 15)) * 8)),
          (AS3 void*)(&sK[b][off]), 16, 0, 0);
    }
#pragma unroll
    for (int i = 0; i < 2; ++i) {
      int off = (tid + i * 512) * 8;
      int r = off >> 6, c = (off >> 3) & 7;
      __builtin_amdgcn_global_load_lds(
          (const AS1 void*)(Vt + (size_t)(kvh * HD + r) * S_LEN + kv0 + ((c ^ (r & 7)) * 8)),
          (AS3 void*)(&sV[b][off]), 16, 0, 0);
    }
  };

  stage(0, 0);
  __syncthreads();
  int cur = 0;

  for (int t = 0; t < ntiles; ++t) {
    const int kv0 = t * 64;
    if (t + 1 < ntiles) stage(cur ^ 1, kv0 + 64);

    if (kv0 <= qw + 15) {
      f32x4 sacc[4] = {};
      __builtin_amdgcn_s_setprio(1);
#pragma unroll
      for (int kt = 0; kt < 4; ++kt)
#pragma unroll
        for (int ks = 0; ks < 4; ++ks) {
          int elem = (kt * 16 + lr) * 128 + (((4 * ks + lg) ^ lr) * 8);
          bf16x8 kf = *reinterpret_cast<const bf16x8*>(&sK[cur][elem]);
          sacc[kt] = __builtin_amdgcn_mfma_f32_16x16x32_bf16(kf, qf[ks], sacc[kt], 0, 0, 0);
        }
      __builtin_amdgcn_s_setprio(0);

      const bool needMask = (kv0 + 63 > qw);
      const int qg = qw + lr;
      float p[16];
      float tmax = -INFINITY;
#pragma unroll
      for (int kt = 0; kt < 4; ++kt)
#pragma unroll
        for (int r = 0; r < 4; ++r) {
          float v = sacc[kt][r] * S2;
          if (needMask && (kv0 + kt * 16 + lg * 4 + r > qg)) v = -INFINITY;
          p[kt * 4 + r] = v;
          tmax = fmaxf(tmax, v);
        }
      tmax = fmaxf(tmax, __shfl_xor(tmax, 16));
      tmax = fmaxf(tmax, __shfl_xor(tmax, 32));
      if (!__all(tmax <= mrun + 8.0f)) {
        float mnew = fmaxf(mrun, tmax);
        float corr = exp2f(mrun - mnew);
        lrun *= corr;
#pragma unroll
        for (int dt = 0; dt < 8; ++dt) ao[dt] *= corr;
        mrun = mnew;
      }
      float rs = 0.f;
#pragma unroll
      for (int i = 0; i < 16; ++i) { p[i] = exp2f(p[i] - mrun); rs += p[i]; }
      rs += __shfl_xor(rs, 16);
      rs += __shfl_xor(rs, 32);
      lrun += rs;

      unsigned int bfrag[2][4];
#pragma unroll
      for (int g = 0; g < 2; ++g) {
        unsigned int Au = (unsigned)f2bf(p[8 * g + 0]) | ((unsigned)f2bf(p[8 * g + 1]) << 16);
        unsigned int Bu = (unsigned)f2bf(p[8 * g + 2]) | ((unsigned)f2bf(p[8 * g + 3]) << 16);
        unsigned int Cu = (unsigned)f2bf(p[8 * g + 4]) | ((unsigned)f2bf(p[8 * g + 5]) << 16);
        unsigned int Du = (unsigned)f2bf(p[8 * g + 6]) | ((unsigned)f2bf(p[8 * g + 7]) << 16);
        int s0 = (lg & 1) * 2;
        int src0 = lr + 16 * s0, src1 = src0 + 16;
        bool hi = lg >= 2;
        int a0 = __shfl((int)Au, src0), c0 = __shfl((int)Cu, src0);
        int b0 = __shfl((int)Bu, src0), d0 = __shfl((int)Du, src0);
        int a1 = __shfl((int)Au, src1), c1 = __shfl((int)Cu, src1);
        int b1 = __shfl((int)Bu, src1), d1 = __shfl((int)Du, src1);
        bfrag[g][0] = hi ? (unsigned)c0 : (unsigned)a0;
        bfrag[g][1] = hi ? (unsigned)d0 : (unsigned)b0;
        bfrag[g][2] = hi ? (unsigned)c1 : (unsigned)a1;
        bfrag[g][3] = hi ? (unsigned)d1 : (unsigned)b1;
      }

      __builtin_amdgcn_s_setprio(1);
#pragma unroll
      for (int g = 0; g < 2; ++g)
#pragma unroll
        for (int dt = 0; dt < 8; ++dt) {
          int d = dt * 16 + lr;
          int elem = d * 64 + (((4 * g + lg) ^ (lr & 7)) * 8);
          bf16x8 vf = *reinterpret_cast<const bf16x8*>(&sV[cur][elem]);
          ao[dt] = __builtin_amdgcn_mfma_f32_16x16x32_bf16(
              vf, *reinterpret_cast<const bf16x8*>(&bfrag[g]), ao[dt], 0, 0, 0);
        }
      __builtin_amdgcn_s_setprio(0);
    }

    __syncthreads();
    cur ^= 1;
  }

  float inv = 1.0f / lrun;
  int qrow = qw + lr;
#pragma unroll
  for (int dt = 0; dt < 8; ++dt) {
    u16x4 o4;
#pragma unroll
    for (int r = 0; r < 4; ++r) o4[r] = f2bf(ao[dt][r] * inv);
    *reinterpret_cast<u16x4*>(&O[(size_t)qrow * HID + h * HD + dt * 16 + lg * 4]) = o4;
  }
}

// ---------------- launch ----------------
extern "C" void kernel_launch(void* const* d_in, const int* in_sizes, int n_in,
                              void* d_out, int out_size, void* d_ws, size_t ws_size,
                              hipStream_t stream) {
  const float* hs = (const float*)d_in[0];
  // d_in[1] = position_ids (arange, unused: positions derived from row index)
  const float* Wq = (const float*)d_in[2];
  const float* Wk = (const float*)d_in[3];
  const float* Wv = (const float*)d_in[4];
  const float* Wo = (const float*)d_in[5];

  unsigned short* ws = (unsigned short*)d_ws;
  size_t off = 0;
  unsigned short* H16  = ws + off; off += (size_t)S_LEN * HID;     // also attn-out
  unsigned short* Wcat = ws + off; off += (size_t)NQKV * HID;      // Wq|Wk|Wv, later Wo in rows 0..4095
  unsigned short* Qb   = ws + off; off += (size_t)S_LEN * HID;
  unsigned short* Kb   = ws + off; off += (size_t)S_LEN * NKV * HD;
  unsigned short* Vt   = ws + off; off += (size_t)S_LEN * NKV * HD;
  float2* tab = (float2*)(ws + off); off += (size_t)S_LEN * 64 * 2 * 2;

  auto cast = [&](const float* src, unsigned short* dst, size_t n) {
    int n4 = (int)(n / 4);
    cast_f32_bf16<<<(n4 + 255) / 256, 256, 0, stream>>>(src, dst, n4);
  };

  rope_table<<<(S_LEN * 64 + 255) / 256, 256, 0, stream>>>(tab);
  cast(hs, H16, (size_t)S_LEN * HID);
  cast(Wq, Wcat, (size_t)HID * HID);
  cast(Wk, Wcat + (size_t)HID * HID, (size_t)NKV * HD * HID);
  cast(Wv, Wcat + (size_t)(HID + NKV * HD) * HID, (size_t)NKV * HD * HID);

  // fused QKV projection, 256^2 8-phase (V written transposed)
  gemm_qkv256<<<dim3(NQKV / 256, S_LEN / 256), 512, 0, stream>>>(
      H16, Wcat, Qb, Kb, Vt);

  // Wo cast reuses Wcat rows 0..4095 (stream-ordered after QKV GEMM)
  cast(Wo, Wcat, (size_t)HID * HID);

  // RoPE on Q and K (single launch)
  {
    int tot = S_LEN * NH * 64 + S_LEN * NKV * 64;
    rope_all<<<(tot + 255) / 256, 256, 0, stream>>>(Qb, Kb, tab);
  }

  // attention -> H16
  attn_kernel<<<dim3(S_LEN / 128, NH), 512, 0, stream>>>(Qb, Kb, Vt, H16);

  // output projection -> fp32 d_out, 8-phase 128x256 (grid 256 = 1/CU)
  gemm_o256<<<dim3(HID / 256, S_LEN / 128), 512, 0, stream>>>(
      H16, Wcat, (float*)d_out);
}

// Round 8
// 350.412 us; speedup vs baseline: 1.1566x; 1.0277x over previous
//
#include <hip/hip_runtime.h>

typedef __attribute__((ext_vector_type(4))) float f32x4;
typedef __attribute__((ext_vector_type(8))) __bf16 bf16x8;
typedef __attribute__((ext_vector_type(4))) unsigned short u16x4;

#define DEVI static __device__ __forceinline__
#define AS1 __attribute__((address_space(1)))
#define AS3 __attribute__((address_space(3)))

static constexpr int S_LEN = 2048;
static constexpr int HID   = 4096;
static constexpr int NH    = 32;
static constexpr int NKV   = 8;
static constexpr int HD    = 128;
static constexpr int NQKV  = HID + 2 * NKV * HD;   // 6144

DEVI unsigned short f2bf(float f) {
  unsigned int u = __float_as_uint(f);
  u += 0x7FFFu + ((u >> 16) & 1u);
  return (unsigned short)(u >> 16);
}
DEVI float bf2f(unsigned short h) {
  return __uint_as_float(((unsigned int)h) << 16);
}

// ---------------- fp32 -> bf16 cast (float4 vectorized) ----------------
__global__ void cast_f32_bf16(const float* __restrict__ in,
                              unsigned short* __restrict__ out, int n4) {
  int i = blockIdx.x * 256 + threadIdx.x;
  if (i >= n4) return;
  float4 v = reinterpret_cast<const float4*>(in)[i];
  u16x4 o;
  o[0] = f2bf(v.x); o[1] = f2bf(v.y); o[2] = f2bf(v.z); o[3] = f2bf(v.w);
  reinterpret_cast<u16x4*>(out)[i] = o;
}

// ---------------- RoPE cos/sin table [S][64] float2 ----------------
__global__ void rope_table(float2* __restrict__ tab) {
  int i = blockIdx.x * 256 + threadIdx.x;
  if (i >= S_LEN * 64) return;
  int j = i & 63, s = i >> 6;
  float inv = powf(10000.0f, -(float)j / 64.0f);
  float ang = (float)s * inv;
  tab[i] = make_float2(cosf(ang), sinf(ang));
}

// ---------------- RoPE in place on bf16 Q and K (one launch) ----------------
__global__ void rope_all(unsigned short* __restrict__ Qb,
                         unsigned short* __restrict__ Kb,
                         const float2* __restrict__ tab) {
  const int totq = S_LEN * NH * 64;
  const int tot  = totq + S_LEN * NKV * 64;
  int i = blockIdx.x * 256 + threadIdx.x;
  if (i >= tot) return;
  unsigned short* X; int Hn, idx;
  if (i < totq) { X = Qb; Hn = NH; idx = i; }
  else          { X = Kb; Hn = NKV; idx = i - totq; }
  int j = idx & 63;
  int h = (idx >> 6) % Hn;
  int s = idx / (64 * Hn);
  float2 cs = tab[s * 64 + j];
  unsigned short* p = X + (size_t)s * Hn * HD + h * HD;
  float x1 = bf2f(p[j]);
  float x2 = bf2f(p[j + 64]);
  p[j]      = f2bf(x1 * cs.x - x2 * cs.y);
  p[j + 64] = f2bf(x2 * cs.x + x1 * cs.y);
}

// ======== fused QKV GEMM, 128x192 tile, BK=64, 8-wave, 8-phase, 2 blk/CU ======
// C[2048 x 6144] = H @ Wcat^T, routed per 16-col fragment to Q / K / V^T.
// Grid (32, 16) = 512 blocks; LDS 40 KB/buf (dbuf 80 KB) -> EXACTLY 2 blocks/CU
// (16 waves/CU): r7 analysis showed the 256^2 kernel's real limit was fill
// (192 blocks @ 1/CU = 64 idle CUs). Cross-block overlap also hides phase
// bubbles and the vmcnt drains.
// Layout: A [128][64] @0, B [192][64] @8192 (shorts); both chunk-swizzled
// c^(row&7); staged as five 8 KB units (A u0,u1; B v0,v1,v2), linear dest.
// Waves 2M x 4N -> wave tile 64x48, acc[4][3]; phase (buf,kh,mh): 2 A-reads,
// B frags (3) read at mh0 / register-reused at mh1; 6 MFMA/phase.
// Stage placement: ALL 5 units of tile t+1 -> buf1 at P1 (WAR: buf1's old tile
// last read prev-P8, barrier between); all 5 of t+2 -> buf0 at P5 (old last
// read P4).  Blocking vmcnt(0) at P4 (covers P5-P8 reads of buf1, 3-phase
// cover) and P8 (covers next-P1 reads of buf0).  i==0: P1 skipped (prologue
// staged t0,t1; P4 vmcnt(0) = no-op).  i==31: P5 skipped; P8 = no-op. No peel.
__global__ __launch_bounds__(512, 4) void gemm_qkv192(
    const unsigned short* __restrict__ A,   // [2048][4096]
    const unsigned short* __restrict__ B,   // [6144][4096]
    unsigned short* __restrict__ Qb,
    unsigned short* __restrict__ Kb,
    unsigned short* __restrict__ Vt) {
  __shared__ __align__(16) unsigned short lds[2][20480];  // 40 KB x 2
  const int tid = threadIdx.x;
  const int lane = tid & 63, w = tid >> 6;
  const int wm = w >> 2, wn = w & 3;
  const int lr = lane & 15, lg = lane >> 4;
  const int n0 = blockIdx.x * 192, m0 = blockIdx.y * 128;
  const int Kd = HID;

  const int sAr = tid >> 3, sAp = tid & 7;   // unit row, phys chunk
  auto stA = [&](int buf, int t, int u) {
    int row = u * 64 + sAr;
    __builtin_amdgcn_global_load_lds(
        (const AS1 void*)(A + (size_t)(m0 + row) * Kd + t * 64 + ((sAp ^ (row & 7)) * 8)),
        (AS3 void*)(&lds[buf][row * 64 + sAp * 8]), 16, 0, 0);
  };
  auto stB = [&](int buf, int t, int v) {
    int row = v * 64 + sAr;
    __builtin_amdgcn_global_load_lds(
        (const AS1 void*)(B + (size_t)(n0 + row) * Kd + t * 64 + ((sAp ^ (row & 7)) * 8)),
        (AS3 void*)(&lds[buf][8192 + row * 64 + sAp * 8]), 16, 0, 0);
  };

  // ds_read offsets; row&7 == lr&7 for all fragment rows (frag bases %16==0)
  // A frag j (of mh): (wm*64 + mh*32 + j*16 + lr)*64 + ((kh*4+lg)^(lr&7))*8
  // B frag c:         8192 + (wn*48 + c*16 + lr)*64 + ((kh*4+lg)^(lr&7))*8
  const int arow = (wm * 64 + lr) * 64;
  const int brow = 8192 + (wn * 48 + lr) * 64;
  const int ck0 = ((lg) ^ (lr & 7)) * 8;        // kh=0 chunk
  const int ck1 = ((4 + lg) ^ (lr & 7)) * 8;    // kh=1 chunk

  f32x4 acc[4][3] = {};
  bf16x8 bgr[3];

  // prologue: t0 -> buf0, t1 -> buf1 (10 loads)
#pragma unroll
  for (int u = 0; u < 2; ++u) { stA(0, 0, u); stA(1, 1, u); }
#pragma unroll
  for (int v = 0; v < 3; ++v) { stB(0, 0, v); stB(1, 1, v); }
  asm volatile("s_waitcnt vmcnt(0)" ::: "memory");
  __builtin_amdgcn_s_barrier();

#define QPHASE(BUF, KH, MH, LOADB, WAITOP, ...)                                \
  do {                                                                         \
    const int ck = (KH) ? ck1 : ck0;                                           \
    const unsigned short* ab = &lds[BUF][arow + (MH) * 2048 + ck];             \
    bf16x8 af0 = *reinterpret_cast<const bf16x8*>(ab);                         \
    bf16x8 af1 = *reinterpret_cast<const bf16x8*>(ab + 1024);                  \
    if (LOADB) {                                                               \
      const unsigned short* bb = &lds[BUF][brow + ck];                         \
      bgr[0] = *reinterpret_cast<const bf16x8*>(bb);                           \
      bgr[1] = *reinterpret_cast<const bf16x8*>(bb + 1024);                    \
      bgr[2] = *reinterpret_cast<const bf16x8*>(bb + 2048);                    \
    }                                                                          \
    __builtin_amdgcn_sched_barrier(0);                                         \
    __VA_ARGS__                                                                \
    WAITOP                                                                     \
    __builtin_amdgcn_s_barrier();                                              \
    asm volatile("s_waitcnt lgkmcnt(0)" ::: "memory");                         \
    __builtin_amdgcn_sched_barrier(0);                                         \
    __builtin_amdgcn_s_setprio(1);                                             \
    acc[(MH)*2+0][0] = __builtin_amdgcn_mfma_f32_16x16x32_bf16(af0, bgr[0], acc[(MH)*2+0][0],0,0,0); \
    acc[(MH)*2+0][1] = __builtin_amdgcn_mfma_f32_16x16x32_bf16(af0, bgr[1], acc[(MH)*2+0][1],0,0,0); \
    acc[(MH)*2+0][2] = __builtin_amdgcn_mfma_f32_16x16x32_bf16(af0, bgr[2], acc[(MH)*2+0][2],0,0,0); \
    acc[(MH)*2+1][0] = __builtin_amdgcn_mfma_f32_16x16x32_bf16(af1, bgr[0], acc[(MH)*2+1][0],0,0,0); \
    acc[(MH)*2+1][1] = __builtin_amdgcn_mfma_f32_16x16x32_bf16(af1, bgr[1], acc[(MH)*2+1][1],0,0,0); \
    acc[(MH)*2+1][2] = __builtin_amdgcn_mfma_f32_16x16x32_bf16(af1, bgr[2], acc[(MH)*2+1][2],0,0,0); \
    __builtin_amdgcn_s_setprio(0);                                             \
    __builtin_amdgcn_s_barrier();                                              \
  } while (0)

#define QVM0 asm volatile("s_waitcnt vmcnt(0)" ::: "memory");
#define QNOW

  for (int i = 0; i < 32; ++i) {
    const int t = 2 * i;
    const bool nf = (i != 0), nl = (i != 31);
    QPHASE(0, 0, 0, 1, QNOW, if (nf) { stA(1, t + 1, 0); stA(1, t + 1, 1);
                                       stB(1, t + 1, 0); stB(1, t + 1, 1); stB(1, t + 1, 2); });
    QPHASE(0, 0, 1, 0, QNOW, ;);
    QPHASE(0, 1, 0, 1, QNOW, ;);
    QPHASE(0, 1, 1, 0, QVM0, ;);
    QPHASE(1, 0, 0, 1, QNOW, if (nl) { stA(0, t + 2, 0); stA(0, t + 2, 1);
                                       stB(0, t + 2, 0); stB(0, t + 2, 1); stB(0, t + 2, 2); });
    QPHASE(1, 0, 1, 0, QNOW, ;);
    QPHASE(1, 1, 0, 1, QNOW, ;);
    QPHASE(1, 1, 1, 0, QVM0, ;);
  }
#undef QPHASE
#undef QVM0
#undef QNOW

  // epilogue: route per 16-col fragment (boundaries 4096/5120 are 16-aligned)
#pragma unroll
  for (int ar = 0; ar < 4; ++ar) {
#pragma unroll
    for (int c = 0; c < 3; ++c) {
      const int gcolb = n0 + wn * 48 + c * 16;
      const int gcol = gcolb + lr;
      const int growb = m0 + wm * 64 + ar * 16 + lg * 4;
      if (gcolb < HID) {
#pragma unroll
        for (int rr = 0; rr < 4; ++rr)
          Qb[(size_t)(growb + rr) * HID + gcol] = f2bf(acc[ar][c][rr]);
      } else if (gcolb < HID + NKV * HD) {
#pragma unroll
        for (int rr = 0; rr < 4; ++rr)
          Kb[(size_t)(growb + rr) * (NKV * HD) + (gcol - HID)] = f2bf(acc[ar][c][rr]);
      } else {
        u16x4 o4;
#pragma unroll
        for (int rr = 0; rr < 4; ++rr) o4[rr] = f2bf(acc[ar][c][rr]);
        *reinterpret_cast<u16x4*>(
            &Vt[(size_t)(gcol - HID - NKV * HD) * S_LEN + growb]) = o4;
      }
    }
  }
}

// ======== O-projection GEMM, 128x256 tile, BK=64, 8-wave, 8-phase ========
// (frozen from r7 — verified; see r7 notes)
__global__ __launch_bounds__(512, 2) void gemm_o256(
    const unsigned short* __restrict__ A,   // [2048][4096] bf16
    const unsigned short* __restrict__ B,   // [4096][4096] bf16 (Wo)
    float* __restrict__ C) {                // [2048][4096] fp32
  __shared__ __align__(16) unsigned short lds[2][24576];
  const int tid = threadIdx.x;
  const int lane = tid & 63, w = tid >> 6;
  const int wm = w >> 2, wn = w & 3;
  const int lr = lane & 15, lg = lane >> 4;
  const int m0 = blockIdx.y * 128, n0 = blockIdx.x * 256;
  const int Kd = HID;

  const int sAr = tid >> 3, sAp = tid & 7;
  const int sBn = tid >> 2, sBp = tid & 3;
  auto stA = [&](int buf, int t, int unit) {
    int row = unit * 64 + sAr;
    __builtin_amdgcn_global_load_lds(
        (const AS1 void*)(A + (size_t)(m0 + row) * Kd + t * 64 + ((sAp ^ (row & 7)) * 8)),
        (AS3 void*)(&lds[buf][row * 64 + sAp * 8]), 16, 0, 0);
  };
  auto stB = [&](int buf, int t, int kh, int hb) {
    int n = hb * 128 + sBn;
    __builtin_amdgcn_global_load_lds(
        (const AS1 void*)(B + (size_t)(n0 + n) * Kd + t * 64 + kh * 32 + ((sBp ^ ((n >> 1) & 3)) * 8)),
        (AS3 void*)(&lds[buf][8192 + kh * 8192 + n * 32 + sBp * 8]), 16, 0, 0);
  };

  const int aoffk0 = (wm * 64 + lr) * 64 + ((lg ^ (lr & 7)) * 8);
  const int aoffk1 = (wm * 64 + lr) * 64 + (((4 + lg) ^ (lr & 7)) * 8);
  const int boff   = 8192 + (wn * 64 + lr) * 32 + ((lg ^ ((lr >> 1) & 3)) * 8);

  f32x4 acc[4][4] = {};
  bf16x8 bgr[4];

#pragma unroll
  for (int u = 0; u < 2; ++u) { stA(0, 0, u); stA(1, 1, u); }
#pragma unroll
  for (int kh = 0; kh < 2; ++kh)
#pragma unroll
    for (int hb = 0; hb < 2; ++hb) { stB(0, 0, kh, hb); stB(1, 1, kh, hb); }
  asm volatile("s_waitcnt vmcnt(0)" ::: "memory");
  __builtin_amdgcn_s_barrier();

#define OPHASE(BUF, KH, MH, LOADB, WAITOP, ...)                                \
  do {                                                                         \
    const unsigned short* ab = &lds[BUF][((KH) ? aoffk1 : aoffk0) + (MH) * 2048];\
    bf16x8 af0 = *reinterpret_cast<const bf16x8*>(ab);                         \
    bf16x8 af1 = *reinterpret_cast<const bf16x8*>(ab + 1024);                  \
    if (LOADB) {                                                               \
      const unsigned short* bb = &lds[BUF][boff + (KH) * 8192];                \
      bgr[0] = *reinterpret_cast<const bf16x8*>(bb);                           \
      bgr[1] = *reinterpret_cast<const bf16x8*>(bb + 512);                     \
      bgr[2] = *reinterpret_cast<const bf16x8*>(bb + 1024);                    \
      bgr[3] = *reinterpret_cast<const bf16x8*>(bb + 1536);                    \
    }                                                                          \
    __builtin_amdgcn_sched_barrier(0);                                         \
    __VA_ARGS__                                                                \
    WAITOP                                                                     \
    __builtin_amdgcn_s_barrier();                                              \
    asm volatile("s_waitcnt lgkmcnt(0)" ::: "memory");                         \
    __builtin_amdgcn_sched_barrier(0);                                         \
    __builtin_amdgcn_s_setprio(1);                                             \
    acc[(MH)*2+0][0] = __builtin_amdgcn_mfma_f32_16x16x32_bf16(af0, bgr[0], acc[(MH)*2+0][0],0,0,0); \
    acc[(MH)*2+0][1] = __builtin_amdgcn_mfma_f32_16x16x32_bf16(af0, bgr[1], acc[(MH)*2+0][1],0,0,0); \
    acc[(MH)*2+0][2] = __builtin_amdgcn_mfma_f32_16x16x32_bf16(af0, bgr[2], acc[(MH)*2+0][2],0,0,0); \
    acc[(MH)*2+0][3] = __builtin_amdgcn_mfma_f32_16x16x32_bf16(af0, bgr[3], acc[(MH)*2+0][3],0,0,0); \
    acc[(MH)*2+1][0] = __builtin_amdgcn_mfma_f32_16x16x32_bf16(af1, bgr[0], acc[(MH)*2+1][0],0,0,0); \
    acc[(MH)*2+1][1] = __builtin_amdgcn_mfma_f32_16x16x32_bf16(af1, bgr[1], acc[(MH)*2+1][1],0,0,0); \
    acc[(MH)*2+1][2] = __builtin_amdgcn_mfma_f32_16x16x32_bf16(af1, bgr[2], acc[(MH)*2+1][2],0,0,0); \
    acc[(MH)*2+1][3] = __builtin_amdgcn_mfma_f32_16x16x32_bf16(af1, bgr[3], acc[(MH)*2+1][3],0,0,0); \
    __builtin_amdgcn_s_setprio(0);                                             \
    __builtin_amdgcn_s_barrier();                                              \
  } while (0)

#define VM2 asm volatile("s_waitcnt vmcnt(2)" ::: "memory");
#define VM0 asm volatile("s_waitcnt vmcnt(0)" ::: "memory");
#define NOW

  for (int i = 0; i < 31; ++i) {
    const int t = 2 * i;
    const bool nf = (i != 0);
    OPHASE(0, 0, 0, 1, NOW, if (nf) { stA(1, t + 1, 0); stA(1, t + 1, 1);
                                      stB(1, t + 1, 1, 0); stB(1, t + 1, 1, 1); });
    OPHASE(0, 0, 1, 0, NOW, ;);
    OPHASE(0, 1, 0, 1, NOW, { stB(0, t + 2, 0, 0); stB(0, t + 2, 0, 1); });
    OPHASE(0, 1, 1, 0, VM2, ;);
    OPHASE(1, 0, 0, 1, NOW, { stA(0, t + 2, 0); stA(0, t + 2, 1);
                              stB(0, t + 2, 1, 0); stB(0, t + 2, 1, 1); });
    OPHASE(1, 0, 1, 0, NOW, ;);
    OPHASE(1, 1, 0, 1, NOW, { stB(1, t + 3, 0, 0); stB(1, t + 3, 0, 1); });
    OPHASE(1, 1, 1, 0, VM2, ;);
  }
  {
    const int t = 62;
    OPHASE(0, 0, 0, 1, NOW, { stA(1, t + 1, 0); stA(1, t + 1, 1);
                              stB(1, t + 1, 1, 0); stB(1, t + 1, 1, 1); });
    OPHASE(0, 0, 1, 0, NOW, ;);
    OPHASE(0, 1, 0, 1, NOW, ;);
    OPHASE(0, 1, 1, 0, VM0, ;);
    OPHASE(1, 0, 0, 1, NOW, ;);
    OPHASE(1, 0, 1, 0, NOW, ;);
    OPHASE(1, 1, 0, 1, NOW, ;);
    OPHASE(1, 1, 1, 0, NOW, ;);
  }
#undef OPHASE
#undef VM2
#undef VM0
#undef NOW

#pragma unroll
  for (int ar = 0; ar < 4; ++ar) {
#pragma unroll
    for (int fc = 0; fc < 4; ++fc) {
      const int gcol = n0 + wn * 64 + fc * 16 + lr;
      const int growb = m0 + wm * 64 + ar * 16 + lg * 4;
#pragma unroll
      for (int rr = 0; rr < 4; ++rr)
        C[(size_t)(growb + rr) * HID + gcol] = acc[ar][fc][rr];
    }
  }
}

// ---------------- causal GQA flash attention, swapped-QK^T, 8-wave ----------------
// (frozen)
__global__ __launch_bounds__(512, 4) void attn_kernel(
    const unsigned short* __restrict__ Q,   // [S][NH*HD]
    const unsigned short* __restrict__ Kb,  // [S][NKV*HD]
    const unsigned short* __restrict__ Vt,  // [NKV*HD][S]
    unsigned short* __restrict__ O) {       // [S][NH*HD]
  __shared__ __align__(16) unsigned short sK[2][64 * 128];
  __shared__ __align__(16) unsigned short sV[2][128 * 64];
  const int tid = threadIdx.x;
  const int lane = tid & 63, w = tid >> 6;
  const int lr = lane & 15, lg = lane >> 4;
  const int qt = (int)gridDim.x - 1 - (int)blockIdx.x;
  const int h = blockIdx.y, kvh = h >> 2;
  const int q0 = qt * 128, qw = q0 + w * 16;
  const int KVS = NKV * HD;

  bf16x8 qf[4];
#pragma unroll
  for (int ks = 0; ks < 4; ++ks)
    qf[ks] = *reinterpret_cast<const bf16x8*>(
        &Q[(size_t)(qw + lr) * HID + h * HD + ks * 32 + lg * 8]);

  f32x4 ao[8] = {};
  float mrun = -INFINITY, lrun = 0.f;
  const float S2 = 0.12751745f;  // (1/sqrt(128)) * log2(e)
  const int ntiles = 2 * qt + 2;

  auto stage = [&](int b, int kv0) {
#pragma unroll
    for (int i = 0; i < 2; ++i) {
      int off = (tid + i * 512) * 8;
      int r = off >> 7, c = (off >> 3) & 15;
      __builtin_amdgcn_global_load_lds(
          (const AS1 void*)(Kb + (size_t)(kv0 + r) * KVS + kvh * HD + ((c ^ (r & 15)) * 8)),
          (AS3 void*)(&sK[b][off]), 16, 0, 0);
    }
#pragma unroll
    for (int i = 0; i < 2; ++i) {
      int off = (tid + i * 512) * 8;
      int r = off >> 6, c = (off >> 3) & 7;
      __builtin_amdgcn_global_load_lds(
          (const AS1 void*)(Vt + (size_t)(kvh * HD + r) * S_LEN + kv0 + ((c ^ (r & 7)) * 8)),
          (AS3 void*)(&sV[b][off]), 16, 0, 0);
    }
  };

  stage(0, 0);
  __syncthreads();
  int cur = 0;

  for (int t = 0; t < ntiles; ++t) {
    const int kv0 = t * 64;
    if (t + 1 < ntiles) stage(cur ^ 1, kv0 + 64);

    if (kv0 <= qw + 15) {
      f32x4 sacc[4] = {};
      __builtin_amdgcn_s_setprio(1);
#pragma unroll
      for (int kt = 0; kt < 4; ++kt)
#pragma unroll
        for (int ks = 0; ks < 4; ++ks) {
          int elem = (kt * 16 + lr) * 128 + (((4 * ks + lg) ^ lr) * 8);
          bf16x8 kf = *reinterpret_cast<const bf16x8*>(&sK[cur][elem]);
          sacc[kt] = __builtin_amdgcn_mfma_f32_16x16x32_bf16(kf, qf[ks], sacc[kt], 0, 0, 0);
        }
      __builtin_amdgcn_s_setprio(0);

      const bool needMask = (kv0 + 63 > qw);
      const int qg = qw + lr;
      float p[16];
      float tmax = -INFINITY;
#pragma unroll
      for (int kt = 0; kt < 4; ++kt)
#pragma unroll
        for (int r = 0; r < 4; ++r) {
          float v = sacc[kt][r] * S2;
          if (needMask && (kv0 + kt * 16 + lg * 4 + r > qg)) v = -INFINITY;
          p[kt * 4 + r] = v;
          tmax = fmaxf(tmax, v);
        }
      tmax = fmaxf(tmax, __shfl_xor(tmax, 16));
      tmax = fmaxf(tmax, __shfl_xor(tmax, 32));
      if (!__all(tmax <= mrun + 8.0f)) {
        float mnew = fmaxf(mrun, tmax);
        float corr = exp2f(mrun - mnew);
        lrun *= corr;
#pragma unroll
        for (int dt = 0; dt < 8; ++dt) ao[dt] *= corr;
        mrun = mnew;
      }
      float rs = 0.f;
#pragma unroll
      for (int i = 0; i < 16; ++i) { p[i] = exp2f(p[i] - mrun); rs += p[i]; }
      rs += __shfl_xor(rs, 16);
      rs += __shfl_xor(rs, 32);
      lrun += rs;

      unsigned int bfrag[2][4];
#pragma unroll
      for (int g = 0; g < 2; ++g) {
        unsigned int Au = (unsigned)f2bf(p[8 * g + 0]) | ((unsigned)f2bf(p[8 * g + 1]) << 16);
        unsigned int Bu = (unsigned)f2bf(p[8 * g + 2]) | ((unsigned)f2bf(p[8 * g + 3]) << 16);
        unsigned int Cu = (unsigned)f2bf(p[8 * g + 4]) | ((unsigned)f2bf(p[8 * g + 5]) << 16);
        unsigned int Du = (unsigned)f2bf(p[8 * g + 6]) | ((unsigned)f2bf(p[8 * g + 7]) << 16);
        int s0 = (lg & 1) * 2;
        int src0 = lr + 16 * s0, src1 = src0 + 16;
        bool hi = lg >= 2;
        int a0 = __shfl((int)Au, src0), c0 = __shfl((int)Cu, src0);
        int b0 = __shfl((int)Bu, src0), d0 = __shfl((int)Du, src0);
        int a1 = __shfl((int)Au, src1), c1 = __shfl((int)Cu, src1);
        int b1 = __shfl((int)Bu, src1), d1 = __shfl((int)Du, src1);
        bfrag[g][0] = hi ? (unsigned)c0 : (unsigned)a0;
        bfrag[g][1] = hi ? (unsigned)d0 : (unsigned)b0;
        bfrag[g][2] = hi ? (unsigned)c1 : (unsigned)a1;
        bfrag[g][3] = hi ? (unsigned)d1 : (unsigned)b1;
      }

      __builtin_amdgcn_s_setprio(1);
#pragma unroll
      for (int g = 0; g < 2; ++g)
#pragma unroll
        for (int dt = 0; dt < 8; ++dt) {
          int d = dt * 16 + lr;
          int elem = d * 64 + (((4 * g + lg) ^ (lr & 7)) * 8);
          bf16x8 vf = *reinterpret_cast<const bf16x8*>(&sV[cur][elem]);
          ao[dt] = __builtin_amdgcn_mfma_f32_16x16x32_bf16(
              vf, *reinterpret_cast<const bf16x8*>(&bfrag[g]), ao[dt], 0, 0, 0);
        }
      __builtin_amdgcn_s_setprio(0);
    }

    __syncthreads();
    cur ^= 1;
  }

  float inv = 1.0f / lrun;
  int qrow = qw + lr;
#pragma unroll
  for (int dt = 0; dt < 8; ++dt) {
    u16x4 o4;
#pragma unroll
    for (int r = 0; r < 4; ++r) o4[r] = f2bf(ao[dt][r] * inv);
    *reinterpret_cast<u16x4*>(&O[(size_t)qrow * HID + h * HD + dt * 16 + lg * 4]) = o4;
  }
}

// ---------------- launch ----------------
extern "C" void kernel_launch(void* const* d_in, const int* in_sizes, int n_in,
                              void* d_out, int out_size, void* d_ws, size_t ws_size,
                              hipStream_t stream) {
  const float* hs = (const float*)d_in[0];
  // d_in[1] = position_ids (arange, unused: positions derived from row index)
  const float* Wq = (const float*)d_in[2];
  const float* Wk = (const float*)d_in[3];
  const float* Wv = (const float*)d_in[4];
  const float* Wo = (const float*)d_in[5];

  unsigned short* ws = (unsigned short*)d_ws;
  size_t off = 0;
  unsigned short* H16  = ws + off; off += (size_t)S_LEN * HID;     // also attn-out
  unsigned short* Wcat = ws + off; off += (size_t)NQKV * HID;      // Wq|Wk|Wv, later Wo in rows 0..4095
  unsigned short* Qb   = ws + off; off += (size_t)S_LEN * HID;
  unsigned short* Kb   = ws + off; off += (size_t)S_LEN * NKV * HD;
  unsigned short* Vt   = ws + off; off += (size_t)S_LEN * NKV * HD;
  float2* tab = (float2*)(ws + off); off += (size_t)S_LEN * 64 * 2 * 2;

  auto cast = [&](const float* src, unsigned short* dst, size_t n) {
    int n4 = (int)(n / 4);
    cast_f32_bf16<<<(n4 + 255) / 256, 256, 0, stream>>>(src, dst, n4);
  };

  rope_table<<<(S_LEN * 64 + 255) / 256, 256, 0, stream>>>(tab);
  cast(hs, H16, (size_t)S_LEN * HID);
  cast(Wq, Wcat, (size_t)HID * HID);
  cast(Wk, Wcat + (size_t)HID * HID, (size_t)NKV * HD * HID);
  cast(Wv, Wcat + (size_t)(HID + NKV * HD) * HID, (size_t)NKV * HD * HID);

  // fused QKV projection, 128x192 8-phase, 512 blocks = 2/CU
  gemm_qkv192<<<dim3(NQKV / 192, S_LEN / 128), 512, 0, stream>>>(
      H16, Wcat, Qb, Kb, Vt);

  // Wo cast reuses Wcat rows 0..4095 (stream-ordered after QKV GEMM)
  cast(Wo, Wcat, (size_t)HID * HID);

  // RoPE on Q and K (single launch)
  {
    int tot = S_LEN * NH * 64 + S_LEN * NKV * 64;
    rope_all<<<(tot + 255) / 256, 256, 0, stream>>>(Qb, Kb, tab);
  }

  // attention -> H16
  attn_kernel<<<dim3(S_LEN / 128, NH), 512, 0, stream>>>(Qb, Kb, Vt, H16);

  // output projection -> fp32 d_out, 8-phase 128x256 (grid 256 = 1/CU)
  gemm_o256<<<dim3(HID / 256, S_LEN / 128), 512, 0, stream>>>(
      H16, Wcat, (float*)d_out);
}

// Round 9
// 323.207 us; speedup vs baseline: 1.2540x; 1.0842x over previous
//
#include <hip/hip_runtime.h>

typedef __attribute__((ext_vector_type(4))) float f32x4;
typedef __attribute__((ext_vector_type(8))) __bf16 bf16x8;
typedef __attribute__((ext_vector_type(4))) unsigned short u16x4;

#define DEVI static __device__ __forceinline__
#define AS1 __attribute__((address_space(1)))
#define AS3 __attribute__((address_space(3)))

static constexpr int S_LEN = 2048;
static constexpr int HID   = 4096;
static constexpr int NH    = 32;
static constexpr int NKV   = 8;
static constexpr int HD    = 128;
static constexpr int NQKV  = HID + 2 * NKV * HD;   // 6144

DEVI unsigned short f2bf(float f) {
  unsigned int u = __float_as_uint(f);
  u += 0x7FFFu + ((u >> 16) & 1u);
  return (unsigned short)(u >> 16);
}
DEVI float bf2f(unsigned short h) {
  return __uint_as_float(((unsigned int)h) << 16);
}

// ---------------- fp32 -> bf16 cast (float4 vectorized) ----------------
__global__ void cast_f32_bf16(const float* __restrict__ in,
                              unsigned short* __restrict__ out, int n4) {
  int i = blockIdx.x * 256 + threadIdx.x;
  if (i >= n4) return;
  float4 v = reinterpret_cast<const float4*>(in)[i];
  u16x4 o;
  o[0] = f2bf(v.x); o[1] = f2bf(v.y); o[2] = f2bf(v.z); o[3] = f2bf(v.w);
  reinterpret_cast<u16x4*>(out)[i] = o;
}

// ---------------- RoPE cos/sin table [S][64] float2 ----------------
__global__ void rope_table(float2* __restrict__ tab) {
  int i = blockIdx.x * 256 + threadIdx.x;
  if (i >= S_LEN * 64) return;
  int j = i & 63, s = i >> 6;
  float inv = powf(10000.0f, -(float)j / 64.0f);
  float ang = (float)s * inv;
  tab[i] = make_float2(cosf(ang), sinf(ang));
}

// ---------------- RoPE in place on bf16 Q and K (one launch) ----------------
__global__ void rope_all(unsigned short* __restrict__ Qb,
                         unsigned short* __restrict__ Kb,
                         const float2* __restrict__ tab) {
  const int totq = S_LEN * NH * 64;
  const int tot  = totq + S_LEN * NKV * 64;
  int i = blockIdx.x * 256 + threadIdx.x;
  if (i >= tot) return;
  unsigned short* X; int Hn, idx;
  if (i < totq) { X = Qb; Hn = NH; idx = i; }
  else          { X = Kb; Hn = NKV; idx = i - totq; }
  int j = idx & 63;
  int h = (idx >> 6) % Hn;
  int s = idx / (64 * Hn);
  float2 cs = tab[s * 64 + j];
  unsigned short* p = X + (size_t)s * Hn * HD + h * HD;
  float x1 = bf2f(p[j]);
  float x2 = bf2f(p[j + 64]);
  p[j]      = f2bf(x1 * cs.x - x2 * cs.y);
  p[j + 64] = f2bf(x2 * cs.x + x1 * cs.y);
}

// ======== fused QKV GEMM, 128x192 tile, BK=64, 8-wave, 8-phase, 2 blk/CU ======
// (frozen from r8; see r8 notes)
__global__ __launch_bounds__(512, 4) void gemm_qkv192(
    const unsigned short* __restrict__ A,   // [2048][4096]
    const unsigned short* __restrict__ B,   // [6144][4096]
    unsigned short* __restrict__ Qb,
    unsigned short* __restrict__ Kb,
    unsigned short* __restrict__ Vt) {
  __shared__ __align__(16) unsigned short lds[2][20480];  // 40 KB x 2
  const int tid = threadIdx.x;
  const int lane = tid & 63, w = tid >> 6;
  const int wm = w >> 2, wn = w & 3;
  const int lr = lane & 15, lg = lane >> 4;
  const int n0 = blockIdx.x * 192, m0 = blockIdx.y * 128;
  const int Kd = HID;

  const int sAr = tid >> 3, sAp = tid & 7;   // unit row, phys chunk
  auto stA = [&](int buf, int t, int u) {
    int row = u * 64 + sAr;
    __builtin_amdgcn_global_load_lds(
        (const AS1 void*)(A + (size_t)(m0 + row) * Kd + t * 64 + ((sAp ^ (row & 7)) * 8)),
        (AS3 void*)(&lds[buf][row * 64 + sAp * 8]), 16, 0, 0);
  };
  auto stB = [&](int buf, int t, int v) {
    int row = v * 64 + sAr;
    __builtin_amdgcn_global_load_lds(
        (const AS1 void*)(B + (size_t)(n0 + row) * Kd + t * 64 + ((sAp ^ (row & 7)) * 8)),
        (AS3 void*)(&lds[buf][8192 + row * 64 + sAp * 8]), 16, 0, 0);
  };

  const int arow = (wm * 64 + lr) * 64;
  const int brow = 8192 + (wn * 48 + lr) * 64;
  const int ck0 = ((lg) ^ (lr & 7)) * 8;        // kh=0 chunk
  const int ck1 = ((4 + lg) ^ (lr & 7)) * 8;    // kh=1 chunk

  f32x4 acc[4][3] = {};
  bf16x8 bgr[3];

  // prologue: t0 -> buf0, t1 -> buf1 (10 loads)
#pragma unroll
  for (int u = 0; u < 2; ++u) { stA(0, 0, u); stA(1, 1, u); }
#pragma unroll
  for (int v = 0; v < 3; ++v) { stB(0, 0, v); stB(1, 1, v); }
  asm volatile("s_waitcnt vmcnt(0)" ::: "memory");
  __builtin_amdgcn_s_barrier();

#define QPHASE(BUF, KH, MH, LOADB, WAITOP, ...)                                \
  do {                                                                         \
    const int ck = (KH) ? ck1 : ck0;                                           \
    const unsigned short* ab = &lds[BUF][arow + (MH) * 2048 + ck];             \
    bf16x8 af0 = *reinterpret_cast<const bf16x8*>(ab);                         \
    bf16x8 af1 = *reinterpret_cast<const bf16x8*>(ab + 1024);                  \
    if (LOADB) {                                                               \
      const unsigned short* bb = &lds[BUF][brow + ck];                         \
      bgr[0] = *reinterpret_cast<const bf16x8*>(bb);                           \
      bgr[1] = *reinterpret_cast<const bf16x8*>(bb + 1024);                    \
      bgr[2] = *reinterpret_cast<const bf16x8*>(bb + 2048);                    \
    }                                                                          \
    __builtin_amdgcn_sched_barrier(0);                                         \
    __VA_ARGS__                                                                \
    WAITOP                                                                     \
    __builtin_amdgcn_s_barrier();                                              \
    asm volatile("s_waitcnt lgkmcnt(0)" ::: "memory");                         \
    __builtin_amdgcn_sched_barrier(0);                                         \
    __builtin_amdgcn_s_setprio(1);                                             \
    acc[(MH)*2+0][0] = __builtin_amdgcn_mfma_f32_16x16x32_bf16(af0, bgr[0], acc[(MH)*2+0][0],0,0,0); \
    acc[(MH)*2+0][1] = __builtin_amdgcn_mfma_f32_16x16x32_bf16(af0, bgr[1], acc[(MH)*2+0][1],0,0,0); \
    acc[(MH)*2+0][2] = __builtin_amdgcn_mfma_f32_16x16x32_bf16(af0, bgr[2], acc[(MH)*2+0][2],0,0,0); \
    acc[(MH)*2+1][0] = __builtin_amdgcn_mfma_f32_16x16x32_bf16(af1, bgr[0], acc[(MH)*2+1][0],0,0,0); \
    acc[(MH)*2+1][1] = __builtin_amdgcn_mfma_f32_16x16x32_bf16(af1, bgr[1], acc[(MH)*2+1][1],0,0,0); \
    acc[(MH)*2+1][2] = __builtin_amdgcn_mfma_f32_16x16x32_bf16(af1, bgr[2], acc[(MH)*2+1][2],0,0,0); \
    __builtin_amdgcn_s_setprio(0);                                             \
    __builtin_amdgcn_s_barrier();                                              \
  } while (0)

#define QVM0 asm volatile("s_waitcnt vmcnt(0)" ::: "memory");
#define QNOW

  for (int i = 0; i < 32; ++i) {
    const int t = 2 * i;
    const bool nf = (i != 0), nl = (i != 31);
    QPHASE(0, 0, 0, 1, QNOW, if (nf) { stA(1, t + 1, 0); stA(1, t + 1, 1);
                                       stB(1, t + 1, 0); stB(1, t + 1, 1); stB(1, t + 1, 2); });
    QPHASE(0, 0, 1, 0, QNOW, ;);
    QPHASE(0, 1, 0, 1, QNOW, ;);
    QPHASE(0, 1, 1, 0, QVM0, ;);
    QPHASE(1, 0, 0, 1, QNOW, if (nl) { stA(0, t + 2, 0); stA(0, t + 2, 1);
                                       stB(0, t + 2, 0); stB(0, t + 2, 1); stB(0, t + 2, 2); });
    QPHASE(1, 0, 1, 0, QNOW, ;);
    QPHASE(1, 1, 0, 1, QNOW, ;);
    QPHASE(1, 1, 1, 0, QVM0, ;);
  }
#undef QPHASE
#undef QVM0
#undef QNOW

  // epilogue: route per 16-col fragment (boundaries 4096/5120 are 16-aligned)
#pragma unroll
  for (int ar = 0; ar < 4; ++ar) {
#pragma unroll
    for (int c = 0; c < 3; ++c) {
      const int gcolb = n0 + wn * 48 + c * 16;
      const int gcol = gcolb + lr;
      const int growb = m0 + wm * 64 + ar * 16 + lg * 4;
      if (gcolb < HID) {
#pragma unroll
        for (int rr = 0; rr < 4; ++rr)
          Qb[(size_t)(growb + rr) * HID + gcol] = f2bf(acc[ar][c][rr]);
      } else if (gcolb < HID + NKV * HD) {
#pragma unroll
        for (int rr = 0; rr < 4; ++rr)
          Kb[(size_t)(growb + rr) * (NKV * HD) + (gcol - HID)] = f2bf(acc[ar][c][rr]);
      } else {
        u16x4 o4;
#pragma unroll
        for (int rr = 0; rr < 4; ++rr) o4[rr] = f2bf(acc[ar][c][rr]);
        *reinterpret_cast<u16x4*>(
            &Vt[(size_t)(gcol - HID - NKV * HD) * S_LEN + growb]) = o4;
      }
    }
  }
}

// ======== O-projection GEMM, 128x256 tile, BK=64, 8-wave, 8-phase ========
// (frozen from r7 — verified; see r7 notes)
__global__ __launch_bounds__(512, 2) void gemm_o256(
    const unsigned short* __restrict__ A,   // [2048][4096] bf16
    const unsigned short* __restrict__ B,   // [4096][4096] bf16 (Wo)
    float* __restrict__ C) {                // [2048][4096] fp32
  __shared__ __align__(16) unsigned short lds[2][24576];
  const int tid = threadIdx.x;
  const int lane = tid & 63, w = tid >> 6;
  const int wm = w >> 2, wn = w & 3;
  const int lr = lane & 15, lg = lane >> 4;
  const int m0 = blockIdx.y * 128, n0 = blockIdx.x * 256;
  const int Kd = HID;

  const int sAr = tid >> 3, sAp = tid & 7;
  const int sBn = tid >> 2, sBp = tid & 3;
  auto stA = [&](int buf, int t, int unit) {
    int row = unit * 64 + sAr;
    __builtin_amdgcn_global_load_lds(
        (const AS1 void*)(A + (size_t)(m0 + row) * Kd + t * 64 + ((sAp ^ (row & 7)) * 8)),
        (AS3 void*)(&lds[buf][row * 64 + sAp * 8]), 16, 0, 0);
  };
  auto stB = [&](int buf, int t, int kh, int hb) {
    int n = hb * 128 + sBn;
    __builtin_amdgcn_global_load_lds(
        (const AS1 void*)(B + (size_t)(n0 + n) * Kd + t * 64 + kh * 32 + ((sBp ^ ((n >> 1) & 3)) * 8)),
        (AS3 void*)(&lds[buf][8192 + kh * 8192 + n * 32 + sBp * 8]), 16, 0, 0);
  };

  const int aoffk0 = (wm * 64 + lr) * 64 + ((lg ^ (lr & 7)) * 8);
  const int aoffk1 = (wm * 64 + lr) * 64 + (((4 + lg) ^ (lr & 7)) * 8);
  const int boff   = 8192 + (wn * 64 + lr) * 32 + ((lg ^ ((lr >> 1) & 3)) * 8);

  f32x4 acc[4][4] = {};
  bf16x8 bgr[4];

#pragma unroll
  for (int u = 0; u < 2; ++u) { stA(0, 0, u); stA(1, 1, u); }
#pragma unroll
  for (int kh = 0; kh < 2; ++kh)
#pragma unroll
    for (int hb = 0; hb < 2; ++hb) { stB(0, 0, kh, hb); stB(1, 1, kh, hb); }
  asm volatile("s_waitcnt vmcnt(0)" ::: "memory");
  __builtin_amdgcn_s_barrier();

#define OPHASE(BUF, KH, MH, LOADB, WAITOP, ...)                                \
  do {                                                                         \
    const unsigned short* ab = &lds[BUF][((KH) ? aoffk1 : aoffk0) + (MH) * 2048];\
    bf16x8 af0 = *reinterpret_cast<const bf16x8*>(ab);                         \
    bf16x8 af1 = *reinterpret_cast<const bf16x8*>(ab + 1024);                  \
    if (LOADB) {                                                               \
      const unsigned short* bb = &lds[BUF][boff + (KH) * 8192];                \
      bgr[0] = *reinterpret_cast<const bf16x8*>(bb);                           \
      bgr[1] = *reinterpret_cast<const bf16x8*>(bb + 512);                     \
      bgr[2] = *reinterpret_cast<const bf16x8*>(bb + 1024);                    \
      bgr[3] = *reinterpret_cast<const bf16x8*>(bb + 1536);                    \
    }                                                                          \
    __builtin_amdgcn_sched_barrier(0);                                         \
    __VA_ARGS__                                                                \
    WAITOP                                                                     \
    __builtin_amdgcn_s_barrier();                                              \
    asm volatile("s_waitcnt lgkmcnt(0)" ::: "memory");                         \
    __builtin_amdgcn_sched_barrier(0);                                         \
    __builtin_amdgcn_s_setprio(1);                                             \
    acc[(MH)*2+0][0] = __builtin_amdgcn_mfma_f32_16x16x32_bf16(af0, bgr[0], acc[(MH)*2+0][0],0,0,0); \
    acc[(MH)*2+0][1] = __builtin_amdgcn_mfma_f32_16x16x32_bf16(af0, bgr[1], acc[(MH)*2+0][1],0,0,0); \
    acc[(MH)*2+0][2] = __builtin_amdgcn_mfma_f32_16x16x32_bf16(af0, bgr[2], acc[(MH)*2+0][2],0,0,0); \
    acc[(MH)*2+0][3] = __builtin_amdgcn_mfma_f32_16x16x32_bf16(af0, bgr[3], acc[(MH)*2+0][3],0,0,0); \
    acc[(MH)*2+1][0] = __builtin_amdgcn_mfma_f32_16x16x32_bf16(af1, bgr[0], acc[(MH)*2+1][0],0,0,0); \
    acc[(MH)*2+1][1] = __builtin_amdgcn_mfma_f32_16x16x32_bf16(af1, bgr[1], acc[(MH)*2+1][1],0,0,0); \
    acc[(MH)*2+1][2] = __builtin_amdgcn_mfma_f32_16x16x32_bf16(af1, bgr[2], acc[(MH)*2+1][2],0,0,0); \
    acc[(MH)*2+1][3] = __builtin_amdgcn_mfma_f32_16x16x32_bf16(af1, bgr[3], acc[(MH)*2+1][3],0,0,0); \
    __builtin_amdgcn_s_setprio(0);                                             \
    __builtin_amdgcn_s_barrier();                                              \
  } while (0)

#define VM2 asm volatile("s_waitcnt vmcnt(2)" ::: "memory");
#define VM0 asm volatile("s_waitcnt vmcnt(0)" ::: "memory");
#define NOW

  for (int i = 0; i < 31; ++i) {
    const int t = 2 * i;
    const bool nf = (i != 0);
    OPHASE(0, 0, 0, 1, NOW, if (nf) { stA(1, t + 1, 0); stA(1, t + 1, 1);
                                      stB(1, t + 1, 1, 0); stB(1, t + 1, 1, 1); });
    OPHASE(0, 0, 1, 0, NOW, ;);
    OPHASE(0, 1, 0, 1, NOW, { stB(0, t + 2, 0, 0); stB(0, t + 2, 0, 1); });
    OPHASE(0, 1, 1, 0, VM2, ;);
    OPHASE(1, 0, 0, 1, NOW, { stA(0, t + 2, 0); stA(0, t + 2, 1);
                              stB(0, t + 2, 1, 0); stB(0, t + 2, 1, 1); });
    OPHASE(1, 0, 1, 0, NOW, ;);
    OPHASE(1, 1, 0, 1, NOW, { stB(1, t + 3, 0, 0); stB(1, t + 3, 0, 1); });
    OPHASE(1, 1, 1, 0, VM2, ;);
  }
  {
    const int t = 62;
    OPHASE(0, 0, 0, 1, NOW, { stA(1, t + 1, 0); stA(1, t + 1, 1);
                              stB(1, t + 1, 1, 0); stB(1, t + 1, 1, 1); });
    OPHASE(0, 0, 1, 0, NOW, ;);
    OPHASE(0, 1, 0, 1, NOW, ;);
    OPHASE(0, 1, 1, 0, VM0, ;);
    OPHASE(1, 0, 0, 1, NOW, ;);
    OPHASE(1, 0, 1, 0, NOW, ;);
    OPHASE(1, 1, 0, 1, NOW, ;);
    OPHASE(1, 1, 1, 0, NOW, ;);
  }
#undef OPHASE
#undef VM2
#undef VM0
#undef NOW

#pragma unroll
  for (int ar = 0; ar < 4; ++ar) {
#pragma unroll
    for (int fc = 0; fc < 4; ++fc) {
      const int gcol = n0 + wn * 64 + fc * 16 + lr;
      const int growb = m0 + wm * 64 + ar * 16 + lg * 4;
#pragma unroll
      for (int rr = 0; rr < 4; ++rr)
        C[(size_t)(growb + rr) * HID + gcol] = acc[ar][fc][rr];
    }
  }
}

// ---------------- causal GQA flash attention, swapped-QK^T, 8-wave ----------------
// r9: 1D grid of 512 with COMPLEMENTARY qt pairing. Co-resident pair on a CU
// is (b, b+256) under both round-robin models; mapping gives qt(b)+qt(b+256)=15
// so per-CU causal work is constant (34 tile-units) instead of worst-case 64.
__global__ __launch_bounds__(512, 4) void attn_kernel(
    const unsigned short* __restrict__ Q,   // [S][NH*HD]
    const unsigned short* __restrict__ Kb,  // [S][NKV*HD]
    const unsigned short* __restrict__ Vt,  // [NKV*HD][S]
    unsigned short* __restrict__ O) {       // [S][NH*HD]
  __shared__ __align__(16) unsigned short sK[2][64 * 128];
  __shared__ __align__(16) unsigned short sV[2][128 * 64];
  const int tid = threadIdx.x;
  const int lane = tid & 63, w = tid >> 6;
  const int lr = lane & 15, lg = lane >> 4;
  const int b = blockIdx.x;
  const int half = b >> 8, u = b & 255;
  const int h = u & 31, kvh = (u & 31) >> 2;
  const int j = u >> 5;                       // 0..7
  const int qt = half ? (15 - j) : j;         // pair (b, b+256) sums to 15
  const int q0 = qt * 128, qw = q0 + w * 16;
  const int KVS = NKV * HD;

  bf16x8 qf[4];
#pragma unroll
  for (int ks = 0; ks < 4; ++ks)
    qf[ks] = *reinterpret_cast<const bf16x8*>(
        &Q[(size_t)(qw + lr) * HID + h * HD + ks * 32 + lg * 8]);

  f32x4 ao[8] = {};
  float mrun = -INFINITY, lrun = 0.f;
  const float S2 = 0.12751745f;  // (1/sqrt(128)) * log2(e)
  const int ntiles = 2 * qt + 2;

  auto stage = [&](int bb, int kv0) {
#pragma unroll
    for (int i = 0; i < 2; ++i) {
      int off = (tid + i * 512) * 8;
      int r = off >> 7, c = (off >> 3) & 15;
      __builtin_amdgcn_global_load_lds(
          (const AS1 void*)(Kb + (size_t)(kv0 + r) * KVS + kvh * HD + ((c ^ (r & 15)) * 8)),
          (AS3 void*)(&sK[bb][off]), 16, 0, 0);
    }
#pragma unroll
    for (int i = 0; i < 2; ++i) {
      int off = (tid + i * 512) * 8;
      int r = off >> 6, c = (off >> 3) & 7;
      __builtin_amdgcn_global_load_lds(
          (const AS1 void*)(Vt + (size_t)(kvh * HD + r) * S_LEN + kv0 + ((c ^ (r & 7)) * 8)),
          (AS3 void*)(&sV[bb][off]), 16, 0, 0);
    }
  };

  stage(0, 0);
  __syncthreads();
  int cur = 0;

  for (int t = 0; t < ntiles; ++t) {
    const int kv0 = t * 64;
    if (t + 1 < ntiles) stage(cur ^ 1, kv0 + 64);

    if (kv0 <= qw + 15) {
      f32x4 sacc[4] = {};
      __builtin_amdgcn_s_setprio(1);
#pragma unroll
      for (int kt = 0; kt < 4; ++kt)
#pragma unroll
        for (int ks = 0; ks < 4; ++ks) {
          int elem = (kt * 16 + lr) * 128 + (((4 * ks + lg) ^ lr) * 8);
          bf16x8 kf = *reinterpret_cast<const bf16x8*>(&sK[cur][elem]);
          sacc[kt] = __builtin_amdgcn_mfma_f32_16x16x32_bf16(kf, qf[ks], sacc[kt], 0, 0, 0);
        }
      __builtin_amdgcn_s_setprio(0);

      const bool needMask = (kv0 + 63 > qw);
      const int qg = qw + lr;
      float p[16];
      float tmax = -INFINITY;
#pragma unroll
      for (int kt = 0; kt < 4; ++kt)
#pragma unroll
        for (int r = 0; r < 4; ++r) {
          float v = sacc[kt][r] * S2;
          if (needMask && (kv0 + kt * 16 + lg * 4 + r > qg)) v = -INFINITY;
          p[kt * 4 + r] = v;
          tmax = fmaxf(tmax, v);
        }
      tmax = fmaxf(tmax, __shfl_xor(tmax, 16));
      tmax = fmaxf(tmax, __shfl_xor(tmax, 32));
      if (!__all(tmax <= mrun + 8.0f)) {
        float mnew = fmaxf(mrun, tmax);
        float corr = exp2f(mrun - mnew);
        lrun *= corr;
#pragma unroll
        for (int dt = 0; dt < 8; ++dt) ao[dt] *= corr;
        mrun = mnew;
      }
      float rs = 0.f;
#pragma unroll
      for (int i = 0; i < 16; ++i) { p[i] = exp2f(p[i] - mrun); rs += p[i]; }
      rs += __shfl_xor(rs, 16);
      rs += __shfl_xor(rs, 32);
      lrun += rs;

      unsigned int bfrag[2][4];
#pragma unroll
      for (int g = 0; g < 2; ++g) {
        unsigned int Au = (unsigned)f2bf(p[8 * g + 0]) | ((unsigned)f2bf(p[8 * g + 1]) << 16);
        unsigned int Bu = (unsigned)f2bf(p[8 * g + 2]) | ((unsigned)f2bf(p[8 * g + 3]) << 16);
        unsigned int Cu = (unsigned)f2bf(p[8 * g + 4]) | ((unsigned)f2bf(p[8 * g + 5]) << 16);
        unsigned int Du = (unsigned)f2bf(p[8 * g + 6]) | ((unsigned)f2bf(p[8 * g + 7]) << 16);
        int s0 = (lg & 1) * 2;
        int src0 = lr + 16 * s0, src1 = src0 + 16;
        bool hi = lg >= 2;
        int a0 = __shfl((int)Au, src0), c0 = __shfl((int)Cu, src0);
        int b0 = __shfl((int)Bu, src0), d0 = __shfl((int)Du, src0);
        int a1 = __shfl((int)Au, src1), c1 = __shfl((int)Cu, src1);
        int b1 = __shfl((int)Bu, src1), d1 = __shfl((int)Du, src1);
        bfrag[g][0] = hi ? (unsigned)c0 : (unsigned)a0;
        bfrag[g][1] = hi ? (unsigned)d0 : (unsigned)b0;
        bfrag[g][2] = hi ? (unsigned)c1 : (unsigned)a1;
        bfrag[g][3] = hi ? (unsigned)d1 : (unsigned)b1;
      }

      __builtin_amdgcn_s_setprio(1);
#pragma unroll
      for (int g = 0; g < 2; ++g)
#pragma unroll
        for (int dt = 0; dt < 8; ++dt) {
          int d = dt * 16 + lr;
          int elem = d * 64 + (((4 * g + lg) ^ (lr & 7)) * 8);
          bf16x8 vf = *reinterpret_cast<const bf16x8*>(&sV[cur][elem]);
          ao[dt] = __builtin_amdgcn_mfma_f32_16x16x32_bf16(
              vf, *reinterpret_cast<const bf16x8*>(&bfrag[g]), ao[dt], 0, 0, 0);
        }
      __builtin_amdgcn_s_setprio(0);
    }

    __syncthreads();
    cur ^= 1;
  }

  float inv = 1.0f / lrun;
  int qrow = qw + lr;
#pragma unroll
  for (int dt = 0; dt < 8; ++dt) {
    u16x4 o4;
#pragma unroll
    for (int r = 0; r < 4; ++r) o4[r] = f2bf(ao[dt][r] * inv);
    *reinterpret_cast<u16x4*>(&O[(size_t)qrow * HID + h * HD + dt * 16 + lg * 4]) = o4;
  }
}

// ---------------- launch ----------------
extern "C" void kernel_launch(void* const* d_in, const int* in_sizes, int n_in,
                              void* d_out, int out_size, void* d_ws, size_t ws_size,
                              hipStream_t stream) {
  const float* hs = (const float*)d_in[0];
  // d_in[1] = position_ids (arange, unused: positions derived from row index)
  const float* Wq = (const float*)d_in[2];
  const float* Wk = (const float*)d_in[3];
  const float* Wv = (const float*)d_in[4];
  const float* Wo = (const float*)d_in[5];

  unsigned short* ws = (unsigned short*)d_ws;
  size_t off = 0;
  unsigned short* H16  = ws + off; off += (size_t)S_LEN * HID;     // also attn-out
  unsigned short* Wcat = ws + off; off += (size_t)NQKV * HID;      // Wq|Wk|Wv, later Wo in rows 0..4095
  unsigned short* Qb   = ws + off; off += (size_t)S_LEN * HID;
  unsigned short* Kb   = ws + off; off += (size_t)S_LEN * NKV * HD;
  unsigned short* Vt   = ws + off; off += (size_t)S_LEN * NKV * HD;
  float2* tab = (float2*)(ws + off); off += (size_t)S_LEN * 64 * 2 * 2;

  auto cast = [&](const float* src, unsigned short* dst, size_t n) {
    int n4 = (int)(n / 4);
    cast_f32_bf16<<<(n4 + 255) / 256, 256, 0, stream>>>(src, dst, n4);
  };

  rope_table<<<(S_LEN * 64 + 255) / 256, 256, 0, stream>>>(tab);
  cast(hs, H16, (size_t)S_LEN * HID);
  cast(Wq, Wcat, (size_t)HID * HID);
  cast(Wk, Wcat + (size_t)HID * HID, (size_t)NKV * HD * HID);
  cast(Wv, Wcat + (size_t)(HID + NKV * HD) * HID, (size_t)NKV * HD * HID);

  // fused QKV projection, 128x192 8-phase, 512 blocks = 2/CU
  gemm_qkv192<<<dim3(NQKV / 192, S_LEN / 128), 512, 0, stream>>>(
      H16, Wcat, Qb, Kb, Vt);

  // Wo cast reuses Wcat rows 0..4095 (stream-ordered after QKV GEMM)
  cast(Wo, Wcat, (size_t)HID * HID);

  // RoPE on Q and K (single launch)
  {
    int tot = S_LEN * NH * 64 + S_LEN * NKV * 64;
    rope_all<<<(tot + 255) / 256, 256, 0, stream>>>(Qb, Kb, tab);
  }

  // attention -> H16 (1D grid, complementary causal pairing)
  attn_kernel<<<dim3(512), 512, 0, stream>>>(Qb, Kb, Vt, H16);

  // output projection -> fp32 d_out, 8-phase 128x256 (grid 256 = 1/CU)
  gemm_o256<<<dim3(HID / 256, S_LEN / 128), 512, 0, stream>>>(
      H16, Wcat, (float*)d_out);
}

// Round 10
// 314.666 us; speedup vs baseline: 1.2880x; 1.0271x over previous
//
#include <hip/hip_runtime.h>

typedef __attribute__((ext_vector_type(4))) float f32x4;
typedef __attribute__((ext_vector_type(8))) __bf16 bf16x8;
typedef __attribute__((ext_vector_type(4))) unsigned short u16x4;

#define DEVI static __device__ __forceinline__
#define AS1 __attribute__((address_space(1)))
#define AS3 __attribute__((address_space(3)))

static constexpr int S_LEN = 2048;
static constexpr int HID   = 4096;
static constexpr int NH    = 32;
static constexpr int NKV   = 8;
static constexpr int HD    = 128;
static constexpr int NQKV  = HID + 2 * NKV * HD;   // 6144

DEVI unsigned short f2bf(float f) {
  unsigned int u = __float_as_uint(f);
  u += 0x7FFFu + ((u >> 16) & 1u);
  return (unsigned short)(u >> 16);
}
DEVI float bf2f(unsigned short h) {
  return __uint_as_float(((unsigned int)h) << 16);
}

// ---------------- fp32 -> bf16 cast (float4 vectorized) ----------------
__global__ void cast_f32_bf16(const float* __restrict__ in,
                              unsigned short* __restrict__ out, int n4) {
  int i = blockIdx.x * 256 + threadIdx.x;
  if (i >= n4) return;
  float4 v = reinterpret_cast<const float4*>(in)[i];
  u16x4 o;
  o[0] = f2bf(v.x); o[1] = f2bf(v.y); o[2] = f2bf(v.z); o[3] = f2bf(v.w);
  reinterpret_cast<u16x4*>(out)[i] = o;
}

// ---------------- merged pre-GEMM casts: H, Wq, Wk, Wv in one launch --------
__global__ void cast_all(const float* __restrict__ hs,
                         const float* __restrict__ Wq,
                         const float* __restrict__ Wk,
                         const float* __restrict__ Wv,
                         unsigned short* __restrict__ H16,
                         unsigned short* __restrict__ Wcat) {
  const int nH  = S_LEN * HID / 4;
  const int nWq = HID * HID / 4;
  const int nWkv = NKV * HD * HID / 4;
  int i = blockIdx.x * 256 + threadIdx.x;
  const float* src; unsigned short* dst; int idx;
  if (i < nH)                    { src = hs; dst = H16; idx = i; }
  else if (i < nH + nWq)         { src = Wq; dst = Wcat; idx = i - nH; }
  else if (i < nH + nWq + nWkv)  { src = Wk; dst = Wcat + (size_t)HID * HID; idx = i - nH - nWq; }
  else                           { src = Wv; dst = Wcat + (size_t)(HID + NKV * HD) * HID;
                                   idx = i - nH - nWq - nWkv; }
  float4 v = reinterpret_cast<const float4*>(src)[idx];
  u16x4 o;
  o[0] = f2bf(v.x); o[1] = f2bf(v.y); o[2] = f2bf(v.z); o[3] = f2bf(v.w);
  reinterpret_cast<u16x4*>(dst)[idx] = o;
}

// ---------------- RoPE cos/sin table [S][64] float2 ----------------
__global__ void rope_table(float2* __restrict__ tab) {
  int i = blockIdx.x * 256 + threadIdx.x;
  if (i >= S_LEN * 64) return;
  int j = i & 63, s = i >> 6;
  float inv = powf(10000.0f, -(float)j / 64.0f);
  float ang = (float)s * inv;
  tab[i] = make_float2(cosf(ang), sinf(ang));
}

// ---------------- RoPE in place on bf16 Q and K (one launch) ----------------
__global__ void rope_all(unsigned short* __restrict__ Qb,
                         unsigned short* __restrict__ Kb,
                         const float2* __restrict__ tab) {
  const int totq = S_LEN * NH * 64;
  const int tot  = totq + S_LEN * NKV * 64;
  int i = blockIdx.x * 256 + threadIdx.x;
  if (i >= tot) return;
  unsigned short* X; int Hn, idx;
  if (i < totq) { X = Qb; Hn = NH; idx = i; }
  else          { X = Kb; Hn = NKV; idx = i - totq; }
  int j = idx & 63;
  int h = (idx >> 6) % Hn;
  int s = idx / (64 * Hn);
  float2 cs = tab[s * 64 + j];
  unsigned short* p = X + (size_t)s * Hn * HD + h * HD;
  float x1 = bf2f(p[j]);
  float x2 = bf2f(p[j + 64]);
  p[j]      = f2bf(x1 * cs.x - x2 * cs.y);
  p[j + 64] = f2bf(x2 * cs.x + x1 * cs.y);
}

// ====== fused QKV GEMM, 256x192 tile, wave 64x96, BK=64, 8-phase ======
// r10: r9's gemm_qkv192 was LDS-operand-bound (36.5 B/KFLOP -> 55us LDS floor
// vs 41us MFMA floor; measured 44.7% util). Wave tile 64x96 (4 m-frags x
// 6 n-frags, B reg-reused across mh halves) = 26 B/KFLOP -> LDS floor 39us
// ~= MFMA floor. Tile 256x192 -> grid 32x8 = 256 blocks = EXACT 1/CU fill
// (the r7 gemm_o256 regime). LDS 56 KB/buf, dbuf 112 KB.
// Layout: A [256][64] @0, B [192][64] @16384 shorts; chunk swizzle c^(row&7);
// 7 stage units of 8 KB (A u0..u3, B v0..v2), linear dest (rule 21).
// Phase (buf,kh,mh): 2 A-frag reads + (mh==0: 6 B-frag reads); 12 MFMA.
// Stages: all 7 units of t+1->buf1 at P1 (WAR: buf1 old tile last read
// prev-P8, barrier between); all 7 of t+2->buf0 at P5 (old last read P4).
// Blocking vmcnt(0) at P4 (covers P5-P8 buf1 reads, 3-phase cover) and P8
// (covers next-P1 buf0 reads). i==0: P1 skipped (prologue staged t0,t1;
// P4 vmcnt = no-op). i==31: P5 skipped; P8 = no-op.
__global__ __launch_bounds__(512, 2) void gemm_qkv96(
    const unsigned short* __restrict__ A,   // [2048][4096]
    const unsigned short* __restrict__ B,   // [6144][4096]
    unsigned short* __restrict__ Qb,
    unsigned short* __restrict__ Kb,
    unsigned short* __restrict__ Vt) {
  __shared__ __align__(16) unsigned short lds[2][28672];  // 56 KB x 2
  const int tid = threadIdx.x;
  const int lane = tid & 63, w = tid >> 6;
  const int wm = w >> 1, wn = w & 1;     // 4M x 2N waves
  const int lr = lane & 15, lg = lane >> 4;
  const int n0 = blockIdx.x * 192, m0 = blockIdx.y * 256;
  const int Kd = HID;

  const int sAr = tid >> 3, sAp = tid & 7;   // unit row, phys chunk
  auto stA = [&](int buf, int t, int u) {
    int row = u * 64 + sAr;
    __builtin_amdgcn_global_load_lds(
        (const AS1 void*)(A + (size_t)(m0 + row) * Kd + t * 64 + ((sAp ^ (row & 7)) * 8)),
        (AS3 void*)(&lds[buf][row * 64 + sAp * 8]), 16, 0, 0);
  };
  auto stB = [&](int buf, int t, int v) {
    int row = v * 64 + sAr;
    __builtin_amdgcn_global_load_lds(
        (const AS1 void*)(B + (size_t)(n0 + row) * Kd + t * 64 + ((sAp ^ (row & 7)) * 8)),
        (AS3 void*)(&lds[buf][16384 + row * 64 + sAp * 8]), 16, 0, 0);
  };

  // A frag (mh, f): (wm*64 + mh*32 + f*16 + lr)*64 + ((kh*4+lg)^(lr&7))*8
  // B frag c:       16384 + (wn*96 + c*16 + lr)*64 + ((kh*4+lg)^(lr&7))*8
  const int arow = (wm * 64 + lr) * 64;
  const int brow = 16384 + (wn * 96 + lr) * 64;
  const int ck0 = (lg ^ (lr & 7)) * 8;
  const int ck1 = ((4 + lg) ^ (lr & 7)) * 8;

  f32x4 acc[4][6] = {};
  bf16x8 bgr[6];

  // prologue: t0 -> buf0, t1 -> buf1 (14 loads)
#pragma unroll
  for (int u = 0; u < 4; ++u) { stA(0, 0, u); stA(1, 1, u); }
#pragma unroll
  for (int v = 0; v < 3; ++v) { stB(0, 0, v); stB(1, 1, v); }
  asm volatile("s_waitcnt vmcnt(0)" ::: "memory");
  __builtin_amdgcn_s_barrier();

#define QPHASE(BUF, KH, MH, LOADB, WAITOP, ...)                                \
  do {                                                                         \
    const int ck = (KH) ? ck1 : ck0;                                           \
    const unsigned short* ab = &lds[BUF][arow + (MH) * 2048 + ck];             \
    bf16x8 af0 = *reinterpret_cast<const bf16x8*>(ab);                         \
    bf16x8 af1 = *reinterpret_cast<const bf16x8*>(ab + 1024);                  \
    if (LOADB) {                                                               \
      const unsigned short* bb = &lds[BUF][brow + ck];                         \
      bgr[0] = *reinterpret_cast<const bf16x8*>(bb);                           \
      bgr[1] = *reinterpret_cast<const bf16x8*>(bb + 1024);                    \
      bgr[2] = *reinterpret_cast<const bf16x8*>(bb + 2048);                    \
      bgr[3] = *reinterpret_cast<const bf16x8*>(bb + 3072);                    \
      bgr[4] = *reinterpret_cast<const bf16x8*>(bb + 4096);                    \
      bgr[5] = *reinterpret_cast<const bf16x8*>(bb + 5120);                    \
    }                                                                          \
    __builtin_amdgcn_sched_barrier(0);                                         \
    __VA_ARGS__                                                                \
    WAITOP                                                                     \
    __builtin_amdgcn_s_barrier();                                              \
    asm volatile("s_waitcnt lgkmcnt(0)" ::: "memory");                         \
    __builtin_amdgcn_sched_barrier(0);                                         \
    __builtin_amdgcn_s_setprio(1);                                             \
    acc[(MH)*2+0][0] = __builtin_amdgcn_mfma_f32_16x16x32_bf16(af0, bgr[0], acc[(MH)*2+0][0],0,0,0); \
    acc[(MH)*2+0][1] = __builtin_amdgcn_mfma_f32_16x16x32_bf16(af0, bgr[1], acc[(MH)*2+0][1],0,0,0); \
    acc[(MH)*2+0][2] = __builtin_amdgcn_mfma_f32_16x16x32_bf16(af0, bgr[2], acc[(MH)*2+0][2],0,0,0); \
    acc[(MH)*2+0][3] = __builtin_amdgcn_mfma_f32_16x16x32_bf16(af0, bgr[3], acc[(MH)*2+0][3],0,0,0); \
    acc[(MH)*2+0][4] = __builtin_amdgcn_mfma_f32_16x16x32_bf16(af0, bgr[4], acc[(MH)*2+0][4],0,0,0); \
    acc[(MH)*2+0][5] = __builtin_amdgcn_mfma_f32_16x16x32_bf16(af0, bgr[5], acc[(MH)*2+0][5],0,0,0); \
    acc[(MH)*2+1][0] = __builtin_amdgcn_mfma_f32_16x16x32_bf16(af1, bgr[0], acc[(MH)*2+1][0],0,0,0); \
    acc[(MH)*2+1][1] = __builtin_amdgcn_mfma_f32_16x16x32_bf16(af1, bgr[1], acc[(MH)*2+1][1],0,0,0); \
    acc[(MH)*2+1][2] = __builtin_amdgcn_mfma_f32_16x16x32_bf16(af1, bgr[2], acc[(MH)*2+1][2],0,0,0); \
    acc[(MH)*2+1][3] = __builtin_amdgcn_mfma_f32_16x16x32_bf16(af1, bgr[3], acc[(MH)*2+1][3],0,0,0); \
    acc[(MH)*2+1][4] = __builtin_amdgcn_mfma_f32_16x16x32_bf16(af1, bgr[4], acc[(MH)*2+1][4],0,0,0); \
    acc[(MH)*2+1][5] = __builtin_amdgcn_mfma_f32_16x16x32_bf16(af1, bgr[5], acc[(MH)*2+1][5],0,0,0); \
    __builtin_amdgcn_s_setprio(0);                                             \
    __builtin_amdgcn_s_barrier();                                              \
  } while (0)

#define QVM0 asm volatile("s_waitcnt vmcnt(0)" ::: "memory");
#define QNOW

  for (int i = 0; i < 32; ++i) {
    const int t = 2 * i;
    const bool nf = (i != 0), nl = (i != 31);
    QPHASE(0, 0, 0, 1, QNOW, if (nf) { stA(1, t + 1, 0); stA(1, t + 1, 1);
                                       stA(1, t + 1, 2); stA(1, t + 1, 3);
                                       stB(1, t + 1, 0); stB(1, t + 1, 1); stB(1, t + 1, 2); });
    QPHASE(0, 0, 1, 0, QNOW, ;);
    QPHASE(0, 1, 0, 1, QNOW, ;);
    QPHASE(0, 1, 1, 0, QVM0, ;);
    QPHASE(1, 0, 0, 1, QNOW, if (nl) { stA(0, t + 2, 0); stA(0, t + 2, 1);
                                       stA(0, t + 2, 2); stA(0, t + 2, 3);
                                       stB(0, t + 2, 0); stB(0, t + 2, 1); stB(0, t + 2, 2); });
    QPHASE(1, 0, 1, 0, QNOW, ;);
    QPHASE(1, 1, 0, 1, QNOW, ;);
    QPHASE(1, 1, 1, 0, QVM0, ;);
  }
#undef QPHASE
#undef QVM0
#undef QNOW

  // epilogue: route per 16-col fragment (boundaries 4096/5120 are 16-aligned)
#pragma unroll
  for (int ar = 0; ar < 4; ++ar) {
#pragma unroll
    for (int c = 0; c < 6; ++c) {
      const int gcolb = n0 + wn * 96 + c * 16;
      const int gcol = gcolb + lr;
      const int growb = m0 + wm * 64 + ar * 16 + lg * 4;
      if (gcolb < HID) {
#pragma unroll
        for (int rr = 0; rr < 4; ++rr)
          Qb[(size_t)(growb + rr) * HID + gcol] = f2bf(acc[ar][c][rr]);
      } else if (gcolb < HID + NKV * HD) {
#pragma unroll
        for (int rr = 0; rr < 4; ++rr)
          Kb[(size_t)(growb + rr) * (NKV * HD) + (gcol - HID)] = f2bf(acc[ar][c][rr]);
      } else {
        u16x4 o4;
#pragma unroll
        for (int rr = 0; rr < 4; ++rr) o4[rr] = f2bf(acc[ar][c][rr]);
        *reinterpret_cast<u16x4*>(
            &Vt[(size_t)(gcol - HID - NKV * HD) * S_LEN + growb]) = o4;
      }
    }
  }
}

// ======== O-projection GEMM, 128x256 tile, BK=64, 8-wave, 8-phase ========
// (frozen from r7 — verified; see r7 notes)
__global__ __launch_bounds__(512, 2) void gemm_o256(
    const unsigned short* __restrict__ A,   // [2048][4096] bf16
    const unsigned short* __restrict__ B,   // [4096][4096] bf16 (Wo)
    float* __restrict__ C) {                // [2048][4096] fp32
  __shared__ __align__(16) unsigned short lds[2][24576];
  const int tid = threadIdx.x;
  const int lane = tid & 63, w = tid >> 6;
  const int wm = w >> 2, wn = w & 3;
  const int lr = lane & 15, lg = lane >> 4;
  const int m0 = blockIdx.y * 128, n0 = blockIdx.x * 256;
  const int Kd = HID;

  const int sAr = tid >> 3, sAp = tid & 7;
  const int sBn = tid >> 2, sBp = tid & 3;
  auto stA = [&](int buf, int t, int unit) {
    int row = unit * 64 + sAr;
    __builtin_amdgcn_global_load_lds(
        (const AS1 void*)(A + (size_t)(m0 + row) * Kd + t * 64 + ((sAp ^ (row & 7)) * 8)),
        (AS3 void*)(&lds[buf][row * 64 + sAp * 8]), 16, 0, 0);
  };
  auto stB = [&](int buf, int t, int kh, int hb) {
    int n = hb * 128 + sBn;
    __builtin_amdgcn_global_load_lds(
        (const AS1 void*)(B + (size_t)(n0 + n) * Kd + t * 64 + kh * 32 + ((sBp ^ ((n >> 1) & 3)) * 8)),
        (AS3 void*)(&lds[buf][8192 + kh * 8192 + n * 32 + sBp * 8]), 16, 0, 0);
  };

  const int aoffk0 = (wm * 64 + lr) * 64 + ((lg ^ (lr & 7)) * 8);
  const int aoffk1 = (wm * 64 + lr) * 64 + (((4 + lg) ^ (lr & 7)) * 8);
  const int boff   = 8192 + (wn * 64 + lr) * 32 + ((lg ^ ((lr >> 1) & 3)) * 8);

  f32x4 acc[4][4] = {};
  bf16x8 bgr[4];

#pragma unroll
  for (int u = 0; u < 2; ++u) { stA(0, 0, u); stA(1, 1, u); }
#pragma unroll
  for (int kh = 0; kh < 2; ++kh)
#pragma unroll
    for (int hb = 0; hb < 2; ++hb) { stB(0, 0, kh, hb); stB(1, 1, kh, hb); }
  asm volatile("s_waitcnt vmcnt(0)" ::: "memory");
  __builtin_amdgcn_s_barrier();

#define OPHASE(BUF, KH, MH, LOADB, WAITOP, ...)                                \
  do {                                                                         \
    const unsigned short* ab = &lds[BUF][((KH) ? aoffk1 : aoffk0) + (MH) * 2048];\
    bf16x8 af0 = *reinterpret_cast<const bf16x8*>(ab);                         \
    bf16x8 af1 = *reinterpret_cast<const bf16x8*>(ab + 1024);                  \
    if (LOADB) {                                                               \
      const unsigned short* bb = &lds[BUF][boff + (KH) * 8192];                \
      bgr[0] = *reinterpret_cast<const bf16x8*>(bb);                           \
      bgr[1] = *reinterpret_cast<const bf16x8*>(bb + 512);                     \
      bgr[2] = *reinterpret_cast<const bf16x8*>(bb + 1024);                    \
      bgr[3] = *reinterpret_cast<const bf16x8*>(bb + 1536);                    \
    }                                                                          \
    __builtin_amdgcn_sched_barrier(0);                                         \
    __VA_ARGS__                                                                \
    WAITOP                                                                     \
    __builtin_amdgcn_s_barrier();                                              \
    asm volatile("s_waitcnt lgkmcnt(0)" ::: "memory");                         \
    __builtin_amdgcn_sched_barrier(0);                                         \
    __builtin_amdgcn_s_setprio(1);                                             \
    acc[(MH)*2+0][0] = __builtin_amdgcn_mfma_f32_16x16x32_bf16(af0, bgr[0], acc[(MH)*2+0][0],0,0,0); \
    acc[(MH)*2+0][1] = __builtin_amdgcn_mfma_f32_16x16x32_bf16(af0, bgr[1], acc[(MH)*2+0][1],0,0,0); \
    acc[(MH)*2+0][2] = __builtin_amdgcn_mfma_f32_16x16x32_bf16(af0, bgr[2], acc[(MH)*2+0][2],0,0,0); \
    acc[(MH)*2+0][3] = __builtin_amdgcn_mfma_f32_16x16x32_bf16(af0, bgr[3], acc[(MH)*2+0][3],0,0,0); \
    acc[(MH)*2+1][0] = __builtin_amdgcn_mfma_f32_16x16x32_bf16(af1, bgr[0], acc[(MH)*2+1][0],0,0,0); \
    acc[(MH)*2+1][1] = __builtin_amdgcn_mfma_f32_16x16x32_bf16(af1, bgr[1], acc[(MH)*2+1][1],0,0,0); \
    acc[(MH)*2+1][2] = __builtin_amdgcn_mfma_f32_16x16x32_bf16(af1, bgr[2], acc[(MH)*2+1][2],0,0,0); \
    acc[(MH)*2+1][3] = __builtin_amdgcn_mfma_f32_16x16x32_bf16(af1, bgr[3], acc[(MH)*2+1][3],0,0,0); \
    __builtin_amdgcn_s_setprio(0);                                             \
    __builtin_amdgcn_s_barrier();                                              \
  } while (0)

#define VM2 asm volatile("s_waitcnt vmcnt(2)" ::: "memory");
#define VM0 asm volatile("s_waitcnt vmcnt(0)" ::: "memory");
#define NOW

  for (int i = 0; i < 31; ++i) {
    const int t = 2 * i;
    const bool nf = (i != 0);
    OPHASE(0, 0, 0, 1, NOW, if (nf) { stA(1, t + 1, 0); stA(1, t + 1, 1);
                                      stB(1, t + 1, 1, 0); stB(1, t + 1, 1, 1); });
    OPHASE(0, 0, 1, 0, NOW, ;);
    OPHASE(0, 1, 0, 1, NOW, { stB(0, t + 2, 0, 0); stB(0, t + 2, 0, 1); });
    OPHASE(0, 1, 1, 0, VM2, ;);
    OPHASE(1, 0, 0, 1, NOW, { stA(0, t + 2, 0); stA(0, t + 2, 1);
                              stB(0, t + 2, 1, 0); stB(0, t + 2, 1, 1); });
    OPHASE(1, 0, 1, 0, NOW, ;);
    OPHASE(1, 1, 0, 1, NOW, { stB(1, t + 3, 0, 0); stB(1, t + 3, 0, 1); });
    OPHASE(1, 1, 1, 0, VM2, ;);
  }
  {
    const int t = 62;
    OPHASE(0, 0, 0, 1, NOW, { stA(1, t + 1, 0); stA(1, t + 1, 1);
                              stB(1, t + 1, 1, 0); stB(1, t + 1, 1, 1); });
    OPHASE(0, 0, 1, 0, NOW, ;);
    OPHASE(0, 1, 0, 1, NOW, ;);
    OPHASE(0, 1, 1, 0, VM0, ;);
    OPHASE(1, 0, 0, 1, NOW, ;);
    OPHASE(1, 0, 1, 0, NOW, ;);
    OPHASE(1, 1, 0, 1, NOW, ;);
    OPHASE(1, 1, 1, 0, NOW, ;);
  }
#undef OPHASE
#undef VM2
#undef VM0
#undef NOW

#pragma unroll
  for (int ar = 0; ar < 4; ++ar) {
#pragma unroll
    for (int fc = 0; fc < 4; ++fc) {
      const int gcol = n0 + wn * 64 + fc * 16 + lr;
      const int growb = m0 + wm * 64 + ar * 16 + lg * 4;
#pragma unroll
      for (int rr = 0; rr < 4; ++rr)
        C[(size_t)(growb + rr) * HID + gcol] = acc[ar][fc][rr];
    }
  }
}

// ---------------- causal GQA flash attention, swapped-QK^T, 8-wave ----------------
// (frozen from r9: 1D grid, complementary qt pairing)
__global__ __launch_bounds__(512, 4) void attn_kernel(
    const unsigned short* __restrict__ Q,   // [S][NH*HD]
    const unsigned short* __restrict__ Kb,  // [S][NKV*HD]
    const unsigned short* __restrict__ Vt,  // [NKV*HD][S]
    unsigned short* __restrict__ O) {       // [S][NH*HD]
  __shared__ __align__(16) unsigned short sK[2][64 * 128];
  __shared__ __align__(16) unsigned short sV[2][128 * 64];
  const int tid = threadIdx.x;
  const int lane = tid & 63, w = tid >> 6;
  const int lr = lane & 15, lg = lane >> 4;
  const int b = blockIdx.x;
  const int half = b >> 8, u = b & 255;
  const int h = u & 31, kvh = (u & 31) >> 2;
  const int j = u >> 5;                       // 0..7
  const int qt = half ? (15 - j) : j;         // pair (b, b+256) sums to 15
  const int q0 = qt * 128, qw = q0 + w * 16;
  const int KVS = NKV * HD;

  bf16x8 qf[4];
#pragma unroll
  for (int ks = 0; ks < 4; ++ks)
    qf[ks] = *reinterpret_cast<const bf16x8*>(
        &Q[(size_t)(qw + lr) * HID + h * HD + ks * 32 + lg * 8]);

  f32x4 ao[8] = {};
  float mrun = -INFINITY, lrun = 0.f;
  const float S2 = 0.12751745f;  // (1/sqrt(128)) * log2(e)
  const int ntiles = 2 * qt + 2;

  auto stage = [&](int bb, int kv0) {
#pragma unroll
    for (int i = 0; i < 2; ++i) {
      int off = (tid + i * 512) * 8;
      int r = off >> 7, c = (off >> 3) & 15;
      __builtin_amdgcn_global_load_lds(
          (const AS1 void*)(Kb + (size_t)(kv0 + r) * KVS + kvh * HD + ((c ^ (r & 15)) * 8)),
          (AS3 void*)(&sK[bb][off]), 16, 0, 0);
    }
#pragma unroll
    for (int i = 0; i < 2; ++i) {
      int off = (tid + i * 512) * 8;
      int r = off >> 6, c = (off >> 3) & 7;
      __builtin_amdgcn_global_load_lds(
          (const AS1 void*)(Vt + (size_t)(kvh * HD + r) * S_LEN + kv0 + ((c ^ (r & 7)) * 8)),
          (AS3 void*)(&sV[bb][off]), 16, 0, 0);
    }
  };

  stage(0, 0);
  __syncthreads();
  int cur = 0;

  for (int t = 0; t < ntiles; ++t) {
    const int kv0 = t * 64;
    if (t + 1 < ntiles) stage(cur ^ 1, kv0 + 64);

    if (kv0 <= qw + 15) {
      f32x4 sacc[4] = {};
      __builtin_amdgcn_s_setprio(1);
#pragma unroll
      for (int kt = 0; kt < 4; ++kt)
#pragma unroll
        for (int ks = 0; ks < 4; ++ks) {
          int elem = (kt * 16 + lr) * 128 + (((4 * ks + lg) ^ lr) * 8);
          bf16x8 kf = *reinterpret_cast<const bf16x8*>(&sK[cur][elem]);
          sacc[kt] = __builtin_amdgcn_mfma_f32_16x16x32_bf16(kf, qf[ks], sacc[kt], 0, 0, 0);
        }
      __builtin_amdgcn_s_setprio(0);

      const bool needMask = (kv0 + 63 > qw);
      const int qg = qw + lr;
      float p[16];
      float tmax = -INFINITY;
#pragma unroll
      for (int kt = 0; kt < 4; ++kt)
#pragma unroll
        for (int r = 0; r < 4; ++r) {
          float v = sacc[kt][r] * S2;
          if (needMask && (kv0 + kt * 16 + lg * 4 + r > qg)) v = -INFINITY;
          p[kt * 4 + r] = v;
          tmax = fmaxf(tmax, v);
        }
      tmax = fmaxf(tmax, __shfl_xor(tmax, 16));
      tmax = fmaxf(tmax, __shfl_xor(tmax, 32));
      if (!__all(tmax <= mrun + 8.0f)) {
        float mnew = fmaxf(mrun, tmax);
        float corr = exp2f(mrun - mnew);
        lrun *= corr;
#pragma unroll
        for (int dt = 0; dt < 8; ++dt) ao[dt] *= corr;
        mrun = mnew;
      }
      float rs = 0.f;
#pragma unroll
      for (int i = 0; i < 16; ++i) { p[i] = exp2f(p[i] - mrun); rs += p[i]; }
      rs += __shfl_xor(rs, 16);
      rs += __shfl_xor(rs, 32);
      lrun += rs;

      unsigned int bfrag[2][4];
#pragma unroll
      for (int g = 0; g < 2; ++g) {
        unsigned int Au = (unsigned)f2bf(p[8 * g + 0]) | ((unsigned)f2bf(p[8 * g + 1]) << 16);
        unsigned int Bu = (unsigned)f2bf(p[8 * g + 2]) | ((unsigned)f2bf(p[8 * g + 3]) << 16);
        unsigned int Cu = (unsigned)f2bf(p[8 * g + 4]) | ((unsigned)f2bf(p[8 * g + 5]) << 16);
        unsigned int Du = (unsigned)f2bf(p[8 * g + 6]) | ((unsigned)f2bf(p[8 * g + 7]) << 16);
        int s0 = (lg & 1) * 2;
        int src0 = lr + 16 * s0, src1 = src0 + 16;
        bool hi = lg >= 2;
        int a0 = __shfl((int)Au, src0), c0 = __shfl((int)Cu, src0);
        int b0 = __shfl((int)Bu, src0), d0 = __shfl((int)Du, src0);
        int a1 = __shfl((int)Au, src1), c1 = __shfl((int)Cu, src1);
        int b1 = __shfl((int)Bu, src1), d1 = __shfl((int)Du, src1);
        bfrag[g][0] = hi ? (unsigned)c0 : (unsigned)a0;
        bfrag[g][1] = hi ? (unsigned)d0 : (unsigned)b0;
        bfrag[g][2] = hi ? (unsigned)c1 : (unsigned)a1;
        bfrag[g][3] = hi ? (unsigned)d1 : (unsigned)b1;
      }

      __builtin_amdgcn_s_setprio(1);
#pragma unroll
      for (int g = 0; g < 2; ++g)
#pragma unroll
        for (int dt = 0; dt < 8; ++dt) {
          int d = dt * 16 + lr;
          int elem = d * 64 + (((4 * g + lg) ^ (lr & 7)) * 8);
          bf16x8 vf = *reinterpret_cast<const bf16x8*>(&sV[cur][elem]);
          ao[dt] = __builtin_amdgcn_mfma_f32_16x16x32_bf16(
              vf, *reinterpret_cast<const bf16x8*>(&bfrag[g]), ao[dt], 0, 0, 0);
        }
      __builtin_amdgcn_s_setprio(0);
    }

    __syncthreads();
    cur ^= 1;
  }

  float inv = 1.0f / lrun;
  int qrow = qw + lr;
#pragma unroll
  for (int dt = 0; dt < 8; ++dt) {
    u16x4 o4;
#pragma unroll
    for (int r = 0; r < 4; ++r) o4[r] = f2bf(ao[dt][r] * inv);
    *reinterpret_cast<u16x4*>(&O[(size_t)qrow * HID + h * HD + dt * 16 + lg * 4]) = o4;
  }
}

// ---------------- launch ----------------
extern "C" void kernel_launch(void* const* d_in, const int* in_sizes, int n_in,
                              void* d_out, int out_size, void* d_ws, size_t ws_size,
                              hipStream_t stream) {
  const float* hs = (const float*)d_in[0];
  // d_in[1] = position_ids (arange, unused: positions derived from row index)
  const float* Wq = (const float*)d_in[2];
  const float* Wk = (const float*)d_in[3];
  const float* Wv = (const float*)d_in[4];
  const float* Wo = (const float*)d_in[5];

  unsigned short* ws = (unsigned short*)d_ws;
  size_t off = 0;
  unsigned short* H16  = ws + off; off += (size_t)S_LEN * HID;     // also attn-out
  unsigned short* Wcat = ws + off; off += (size_t)NQKV * HID;      // Wq|Wk|Wv, later Wo in rows 0..4095
  unsigned short* Qb   = ws + off; off += (size_t)S_LEN * HID;
  unsigned short* Kb   = ws + off; off += (size_t)S_LEN * NKV * HD;
  unsigned short* Vt   = ws + off; off += (size_t)S_LEN * NKV * HD;
  float2* tab = (float2*)(ws + off); off += (size_t)S_LEN * 64 * 2 * 2;

  rope_table<<<(S_LEN * 64 + 255) / 256, 256, 0, stream>>>(tab);

  // merged H + Wq + Wk + Wv casts (one launch)
  {
    int n4 = (S_LEN * HID + HID * HID + 2 * NKV * HD * HID) / 4;
    cast_all<<<(n4 + 255) / 256, 256, 0, stream>>>(hs, Wq, Wk, Wv, H16, Wcat);
  }

  // fused QKV projection, 256x192 8-phase, 256 blocks = 1/CU exact fill
  gemm_qkv96<<<dim3(NQKV / 192, S_LEN / 256), 512, 0, stream>>>(
      H16, Wcat, Qb, Kb, Vt);

  // Wo cast reuses Wcat rows 0..4095 (stream-ordered after QKV GEMM)
  {
    int n4 = HID * HID / 4;
    cast_f32_bf16<<<(n4 + 255) / 256, 256, 0, stream>>>(Wo, Wcat, n4);
  }

  // RoPE on Q and K (single launch)
  {
    int tot = S_LEN * NH * 64 + S_LEN * NKV * 64;
    rope_all<<<(tot + 255) / 256, 256, 0, stream>>>(Qb, Kb, tab);
  }

  // attention -> H16 (1D grid, complementary causal pairing)
  attn_kernel<<<dim3(512), 512, 0, stream>>>(Qb, Kb, Vt, H16);

  // output projection -> fp32 d_out, 8-phase 128x256 (grid 256 = 1/CU)
  gemm_o256<<<dim3(HID / 256, S_LEN / 128), 512, 0, stream>>>(
      H16, Wcat, (float*)d_out);
}